// Round 16
// baseline (749.571 us; speedup 1.0000x reference)
//
#include <hip/hip_runtime.h>
#include <math.h>

// Problem constants
#define B_  32
#define L_  1024
#define T_  (B_ * L_)       // 32768 tokens
#define DM_ 128
#define DI_ 256
#define DS_ 16
#define DC_ 4
#define DR_ 8
#define NC_ 10
#define CHUNK_ 32
#define NCH_  (L_ / CHUNK_)   // 32 chunks
#define PSTR_ 64              // projall row stride (bf16): 8 dt | 16 B | 16 C | pad

typedef __bf16 bf16x8 __attribute__((ext_vector_type(8)));
typedef __bf16 bf16x4 __attribute__((ext_vector_type(4)));
typedef __bf16 bf16x2 __attribute__((ext_vector_type(2)));
typedef float f32x4 __attribute__((ext_vector_type(4)));

__device__ __forceinline__ float sigmoidf_(float x) { return 1.0f / (1.0f + __expf(-x)); }
__device__ __forceinline__ float siluf_(float x)    { return x * sigmoidf_(x); }
__device__ __forceinline__ float softplusf_(float x) {
    return (x > 15.0f) ? x : __logf(1.0f + __expf(x));
}
__device__ __forceinline__ float fexp2_(float x) { return __builtin_amdgcn_exp2f(x); }

// async 16B global->LDS (gfx950). dest = wave-uniform base + lane*16.
__device__ __forceinline__ void gload_lds16(const __bf16* g, __bf16* l) {
    __builtin_amdgcn_global_load_lds(
        (const __attribute__((address_space(1))) void*)g,
        (__attribute__((address_space(3))) void*)l, 16, 0, 0);
}

// Stage an R x 64 bf16 tile (row stride `stride`, col offset k0) into LDS with
// XOR-swizzle baked in: LDS (row, sw) holds source (row, sw ^ (row&7)).
template<int R>
__device__ __forceinline__ void stage_async(const __bf16* __restrict__ src,
        __bf16* lds, int k0, int stride, int wid, int lane) {
    constexpr int NI = R / 32;
#pragma unroll
    for (int j = 0; j < NI; ++j) {
        int s0 = (wid * NI + j) * 64;
        int s = s0 + lane;
        int row = s >> 3, sw = s & 7;
        int slot = sw ^ (row & 7);
        gload_lds16(src + (size_t)row * stride + k0 + slot * 8, lds + (size_t)s0 * 8);
    }
}

// ---------------- fused embed + layernorm (layer 0) -------------------------------
// Block = 256 threads = 4 waves; wave per token, lane holds 2 channels.
__global__ __launch_bounds__(256) void k_embed_ln(const float* __restrict__ x,
        const float* __restrict__ Win, const float* __restrict__ bin,
        const float* __restrict__ lnw, const float* __restrict__ lnb,
        float* __restrict__ h, __bf16* __restrict__ z) {
    int wid = threadIdx.x >> 6, lane = threadIdx.x & 63;
    int t = blockIdx.x * 4 + wid;
    int b = t >> 10, l = t & 1023;
    const float* xb = x + (size_t)b * 3 * 1024 + l;
    float x0 = xb[0], x1 = xb[1024], x2 = xb[2048];
    int m = lane * 2;
    float2 v;
    v.x = bin[m]     + x0 * Win[m]     + x1 * Win[128 + m]     + x2 * Win[256 + m];
    v.y = bin[m + 1] + x0 * Win[m + 1] + x1 * Win[128 + m + 1] + x2 * Win[256 + m + 1];
    *(float2*)(h + (size_t)t * 128 + m) = v;
    float s = v.x + v.y, sq = v.x * v.x + v.y * v.y;
#pragma unroll
    for (int off = 1; off < 64; off <<= 1) {
        s += __shfl_xor(s, off);
        sq += __shfl_xor(sq, off);
    }
    float mean = s * (1.0f / 128.0f);
    float var = sq * (1.0f / 128.0f) - mean * mean;
    float rstd = rsqrtf(var + 1e-5f);
    float2 wv = *(const float2*)(lnw + m);
    float2 bv = *(const float2*)(lnb + m);
    bf16x2 o;
    o.x = (__bf16)((v.x - mean) * rstd * wv.x + bv.x);
    o.y = (__bf16)((v.y - mean) * rstd * wv.y + bv.y);
    *(bf16x2*)(z + (size_t)t * 128 + m) = o;
}

// ---------------- merged weight prep ----------------------------------------------
// wt1[lay][n<512][k<128]; wt2[lay][n<128][k<256]; wcat[lay][n<64][k<256]
// (wcat n<40 = xpw col n transposed; else 0).
__global__ __launch_bounds__(256) void k_prep(const float* __restrict__ ipw,
        const float* __restrict__ opw, const float* __restrict__ xpw,
        __bf16* __restrict__ wt1, __bf16* __restrict__ wt2,
        __bf16* __restrict__ wcat) {
    int blk = blockIdx.x;              // 0..1023
    int tid = threadIdx.x;
    int i = blk * 256 + tid;
    {
        int lay = i >> 16, rem = i & 65535, n = rem >> 7, k = rem & 127;
        wt1[i] = (__bf16)ipw[lay * 65536 + k * 512 + n];
    }
    if (i < 131072) {
        int lay = i >> 15, rem = i & 32767, n = rem >> 8, k = rem & 255;
        wt2[i] = (__bf16)opw[lay * 32768 + k * 128 + n];
    }
    if (blk < 256) {
        int lay = blk >> 6, n = blk & 63;
        int k = tid;
        float v = (n < 40) ? xpw[lay * 10240 + k * 40 + n] : 0.0f;
        wcat[(size_t)blk * 256 + k] = (__bf16)v;
    }
}

// ---------------- bf16 MFMA GEMM, BM x 128 tile, BK=64 ---------------------------
// MODE 0 (gemm1, N=512): col<256 -> Cb=xinb raw bf16 (stride 256);
//                        col>=256 -> Zb=sgb silu(v) bf16 (stride 256).
// MODE 2 (gemm2, N=128): Cf += acc + bias (f32); GATE A = y*sg (sg pre-silu'd).
//   WLN: fused LayerNorm -> next zb.   POOL: column-sums -> Pool[bm][128].
template<int BM, int K, int N, int MODE, bool GATE, bool WLN, bool POOL>
__global__ __launch_bounds__(256) void k_gemm_mfma(
        const __bf16* __restrict__ A, const __bf16* __restrict__ G,
        const __bf16* __restrict__ Wt, const float* __restrict__ bias,
        float* __restrict__ Cf, __bf16* __restrict__ Cb,
        const float* __restrict__ lnw, const float* __restrict__ lnb,
        __bf16* __restrict__ Zb, float* __restrict__ Pool) {
    static_assert(!GATE || BM == 32, "GATE staging assumes BM=32");
    static_assert(!WLN || (MODE == 2 && BM == 32 && N == 128), "WLN geometry");
    static_assert(!POOL || (MODE == 2 && BM == 32 && N == 128), "POOL geometry");
    __shared__ __bf16 As[BM * 64];
    __shared__ __bf16 Bs[128 * 64];
    __shared__ float red_s[WLN ? 4 : 1][WLN ? 32 : 1];
    __shared__ float red_q[WLN ? 4 : 1][WLN ? 32 : 1];
    int tid = threadIdx.x;
    int bm = blockIdx.x, bn = blockIdx.y;
    int lane = tid & 63, wid = tid >> 6;
    int lr = lane & 15, lg = lane >> 4;
    constexpr int MF = BM / 16;

    f32x4 acc[MF][2] = {};
    const __bf16* Asrc = A + (size_t)(bm * BM) * K;
    const __bf16* Bsrc = Wt + (size_t)(bn * 128) * K;

    for (int k0 = 0; k0 < K; k0 += 64) {
        if (GATE) {
            int row = tid >> 3, slot = tid & 7;
            int m = bm * BM + row;
            bf16x8 yv = *(const bf16x8*)(A + (size_t)m * K + k0 + slot * 8);
            bf16x8 gv = *(const bf16x8*)(G + (size_t)m * 256 + k0 + slot * 8);
            bf16x8 v;
#pragma unroll
            for (int j = 0; j < 8; ++j)
                v[j] = (__bf16)((float)yv[j] * (float)gv[j]);
            *(bf16x8*)(As + row * 64 + ((slot ^ (row & 7)) * 8)) = v;
        } else {
            stage_async<BM>(Asrc, As, k0, K, wid, lane);
        }
        stage_async<128>(Bsrc, Bs, k0, K, wid, lane);
        __syncthreads();
#pragma unroll
        for (int ks = 0; ks < 2; ++ks) {
            int slotbase = ks * 4 + lg;
            bf16x8 af[MF], bfr[2];
#pragma unroll
            for (int m = 0; m < MF; ++m) {
                int row = m * 16 + lr;
                af[m] = *(const bf16x8*)(As + row * 64 + ((slotbase ^ (row & 7)) * 8));
            }
#pragma unroll
            for (int n = 0; n < 2; ++n) {
                int rn = wid * 32 + n * 16 + lr;
                bfr[n] = *(const bf16x8*)(Bs + rn * 64 + ((slotbase ^ (rn & 7)) * 8));
            }
#pragma unroll
            for (int m = 0; m < MF; ++m)
#pragma unroll
                for (int n = 0; n < 2; ++n)
                    acc[m][n] = __builtin_amdgcn_mfma_f32_16x16x32_bf16(
                        af[m], bfr[n], acc[m][n], 0, 0, 0);
        }
        __syncthreads();
    }
    // ---- epilogue: D[row=(lane>>4)*4+reg][col=lane&15] ----
    float vv[MF][2][4];
#pragma unroll
    for (int m = 0; m < MF; ++m) {
#pragma unroll
        for (int n = 0; n < 2; ++n) {
            int col = bn * 128 + wid * 32 + n * 16 + lr;
            float bv = (MODE == 2) ? bias[col] : 0.0f;
#pragma unroll
            for (int rg = 0; rg < 4; ++rg) {
                int row = bm * BM + m * 16 + lg * 4 + rg;
                float v = acc[m][n][rg];
                if (MODE == 0) {
                    if (col < 256)
                        Cb[(size_t)row * 256 + col] = (__bf16)v;
                    else
                        Zb[(size_t)row * 256 + (col - 256)] = (__bf16)siluf_(v);
                } else {
                    float* cp = Cf + (size_t)row * N + col;
                    v += *cp + bv;
                    *cp = v;
                    vv[m][n][rg] = v;
                }
            }
        }
    }
    if (WLN) {
        float ps[MF][4], pq[MF][4];
#pragma unroll
        for (int m = 0; m < MF; ++m)
#pragma unroll
            for (int rg = 0; rg < 4; ++rg) {
                float a = vv[m][0][rg], bv2 = vv[m][1][rg];
                ps[m][rg] = a + bv2;
                pq[m][rg] = a * a + bv2 * bv2;
            }
#pragma unroll
        for (int off = 1; off < 16; off <<= 1) {
#pragma unroll
            for (int m = 0; m < MF; ++m)
#pragma unroll
                for (int rg = 0; rg < 4; ++rg) {
                    ps[m][rg] += __shfl_xor(ps[m][rg], off);
                    pq[m][rg] += __shfl_xor(pq[m][rg], off);
                }
        }
        if (lr == 0) {
#pragma unroll
            for (int m = 0; m < MF; ++m)
#pragma unroll
                for (int rg = 0; rg < 4; ++rg) {
                    int rl = m * 16 + lg * 4 + rg;
                    red_s[wid][rl] = ps[m][rg];
                    red_q[wid][rl] = pq[m][rg];
                }
        }
        __syncthreads();
#pragma unroll
        for (int m = 0; m < MF; ++m)
#pragma unroll
            for (int rg = 0; rg < 4; ++rg) {
                int rl = m * 16 + lg * 4 + rg;
                float s = red_s[0][rl] + red_s[1][rl] + red_s[2][rl] + red_s[3][rl];
                float q = red_q[0][rl] + red_q[1][rl] + red_q[2][rl] + red_q[3][rl];
                float mean = s * (1.0f / 128.0f);
                float var = q * (1.0f / 128.0f) - mean * mean;
                float rstd = rsqrtf(var + 1e-5f);
#pragma unroll
                for (int n = 0; n < 2; ++n) {
                    int col = wid * 32 + n * 16 + lr;
                    float z = (vv[m][n][rg] - mean) * rstd * lnw[col] + lnb[col];
                    Zb[(size_t)(bm * BM + rl) * 128 + col] = (__bf16)z;
                }
            }
    }
    if (POOL) {
        // column sums of this block's 32 rows -> Pool[bm][col]
#pragma unroll
        for (int n = 0; n < 2; ++n) {
            float s = 0.0f;
#pragma unroll
            for (int m = 0; m < MF; ++m)
#pragma unroll
                for (int rg = 0; rg < 4; ++rg) s += vv[m][n][rg];
            s += __shfl_xor(s, 16);
            s += __shfl_xor(s, 32);      // now summed over lg = all 32 rows
            if (lg == 0)
                Pool[(size_t)bm * 128 + wid * 32 + n * 16 + lr] = s;
        }
    }
}

// ---------------- fused causal dwconv(4)+SiLU + x_proj ---------------------------
// 16 tokens/block, 256 threads, grid T/16.
// Phase 1: conv+silu -> xcb (bf16) + xcs (f32 LDS).
// Phase 2: proj[t][0..39] = xc[t] . wcat[n] -> projall (bf16, stride PSTR_).
__global__ __launch_bounds__(256) void k_convproj(const __bf16* __restrict__ xinb,
        const float* __restrict__ cw, const float* __restrict__ cb,
        const __bf16* __restrict__ wcat, __bf16* __restrict__ xcb,
        __bf16* __restrict__ projall) {
    __shared__ float xcs[16 * 257];          // 16.4 KB
    __shared__ __bf16 wlds[40 * 264];        // 21.1 KB (row stride 264: 2-way banks)
    int tid = threadIdx.x;
    int t0 = blockIdx.x * 16;
    // stage weights 40x256
#pragma unroll
    for (int r = 0; r < 5; ++r) {
        int item = r * 256 + tid;            // < 1280
        int n = item >> 5, g8 = (item & 31) * 8;
        *(bf16x8*)(wlds + n * 264 + g8) = *(const bf16x8*)(wcat + n * 256 + g8);
    }
    // conv: thread = (token tl, 16 channels at c0)
    int tl = tid >> 4, c0 = (tid & 15) * 16;
    int t = t0 + tl;
    int l = t & 1023;
    const __bf16* xp = xinb + (size_t)t * 256 + c0;
    float accv[16];
#pragma unroll
    for (int j = 0; j < 16; ++j) accv[j] = cb[c0 + j];
#pragma unroll
    for (int k = 0; k < 4; ++k) {            // tap k uses x[t-(3-k)]
        int back = 3 - k;
        if (l >= back) {
            bf16x8 v0 = *(const bf16x8*)(xp - back * 256);
            bf16x8 v1 = *(const bf16x8*)(xp - back * 256 + 8);
#pragma unroll
            for (int j = 0; j < 8; ++j) {
                accv[j]     = fmaf((float)v0[j], cw[(c0 + j) * 4 + k], accv[j]);
                accv[8 + j] = fmaf((float)v1[j], cw[(c0 + 8 + j) * 4 + k], accv[8 + j]);
            }
        }
    }
    bf16x8 o0, o1;
#pragma unroll
    for (int j = 0; j < 8; ++j) {
        float v = siluf_(accv[j]);
        o0[j] = (__bf16)v; xcs[tl * 257 + c0 + j] = v;
    }
#pragma unroll
    for (int j = 0; j < 8; ++j) {
        float v = siluf_(accv[8 + j]);
        o1[j] = (__bf16)v; xcs[tl * 257 + c0 + 8 + j] = v;
    }
    *(bf16x8*)(xcb + (size_t)t * 256 + c0)     = o0;
    *(bf16x8*)(xcb + (size_t)t * 256 + c0 + 8) = o1;
    __syncthreads();
    // proj: 16 threads per token; thread handles cols {q, q+16, q+32(<40)}
    int q = tid & 15;
    bool has2 = q < 8;
    float acc0 = 0.0f, acc1 = 0.0f, acc2 = 0.0f;
    const __bf16* w0 = wlds + q * 264;
    const __bf16* w1 = wlds + (q + 16) * 264;
    const __bf16* w2 = wlds + (q + 32) * 264;
#pragma unroll 4
    for (int k8 = 0; k8 < 256; k8 += 8) {
        float xv[8];
#pragma unroll
        for (int j = 0; j < 8; ++j) xv[j] = xcs[tl * 257 + k8 + j];
        bf16x8 a = *(const bf16x8*)(w0 + k8);
        bf16x8 b = *(const bf16x8*)(w1 + k8);
#pragma unroll
        for (int j = 0; j < 8; ++j) {
            acc0 = fmaf(xv[j], (float)a[j], acc0);
            acc1 = fmaf(xv[j], (float)b[j], acc1);
        }
        if (has2) {
            bf16x8 c2 = *(const bf16x8*)(w2 + k8);
#pragma unroll
            for (int j = 0; j < 8; ++j) acc2 = fmaf(xv[j], (float)c2[j], acc2);
        }
    }
    __bf16* pr = projall + (size_t)t * PSTR_;
    pr[q] = (__bf16)acc0;
    pr[q + 16] = (__bf16)acc1;
    if (has2) pr[q + 32] = (__bf16)acc2;
}

// ---------------- chunk-parallel SSM scan: one thread per d ----------------------
// projall rows: [0..7]=dt, [8..23]=B, [24..39]=C (bf16, stride PSTR_=64).
// delta computed inline: softplus(dt . dtw[:,d] + dtb[d]).
template<bool FINAL>
__global__ __launch_bounds__(128) void k_scan_chunk(
        const __bf16* __restrict__ projall, const __bf16* __restrict__ xcb,
        const float* __restrict__ dtw, const float* __restrict__ dtb,
        const float* __restrict__ Alog, const float* __restrict__ Dp,
        float* __restrict__ P, float* __restrict__ S,
        __bf16* __restrict__ yb) {
    __shared__ __bf16 xcs[CHUNK_ * 128];        // 8 KB
    __shared__ float bc[CHUNK_ * 32];           // 4 KB
    __shared__ float dts[CHUNK_ * 8];           // 1 KB
    int b = blockIdx.z, c = blockIdx.y, dg = blockIdx.x;   // dg in {0,1}
    int tid = threadIdx.x;                      // 0..127
    int d = dg * 128 + tid;

    const __bf16* projC = projall + ((size_t)b * 1024 + c * CHUNK_) * PSTR_;
    const __bf16* xcC   = xcb + ((size_t)b * 1024 + c * CHUNK_) * 256 + dg * 128;

#pragma unroll
    for (int r = 0; r < (CHUNK_ * 16) / 128; ++r) {
        int item = r * 128 + tid;
        int t = item >> 4, o8 = (item & 15) * 8;
        *(bf16x8*)(xcs + t * 128 + o8) = *(const bf16x8*)(xcC + (size_t)t * 256 + o8);
    }
    {
        int t = tid >> 2, g8 = (tid & 3) * 8;
        bf16x8 v = *(const bf16x8*)(projC + (size_t)t * PSTR_ + 8 + g8);
        float4 f0 = {(float)v[0], (float)v[1], (float)v[2], (float)v[3]};
        float4 f1 = {(float)v[4], (float)v[5], (float)v[6], (float)v[7]};
        *(float4*)(bc + t * 32 + g8)     = f0;
        *(float4*)(bc + t * 32 + g8 + 4) = f1;
    }
    if (tid < CHUNK_) {
        bf16x8 v = *(const bf16x8*)(projC + (size_t)tid * PSTR_);
#pragma unroll
        for (int j = 0; j < 8; ++j) dts[tid * 8 + j] = (float)v[j];
    }

    float dtwc[8];
#pragma unroll
    for (int r = 0; r < 8; ++r) dtwc[r] = dtw[r * 256 + d];
    float dtbd = dtb[d];
    float aa[16], hs[16];
#pragma unroll
    for (int jj = 0; jj < 4; ++jj) {
        float4 av = *(const float4*)(Alog + (size_t)d * 16 + jj * 4);
        aa[jj * 4 + 0] = -__expf(av.x) * 1.44269504088896f;
        aa[jj * 4 + 1] = -__expf(av.y) * 1.44269504088896f;
        aa[jj * 4 + 2] = -__expf(av.z) * 1.44269504088896f;
        aa[jj * 4 + 3] = -__expf(av.w) * 1.44269504088896f;
    }
    float Dpd = Dp[d];
    size_t psIdx = ((size_t)(b * NCH_ + c)) * 4096 + (size_t)d * 16;
    if (FINAL) {
#pragma unroll
        for (int jj = 0; jj < 4; ++jj) {
            float4 h0 = *(const float4*)(P + psIdx + jj * 4);
            hs[jj * 4 + 0] = h0.x; hs[jj * 4 + 1] = h0.y;
            hs[jj * 4 + 2] = h0.z; hs[jj * 4 + 3] = h0.w;
        }
    } else {
#pragma unroll
        for (int j = 0; j < 16; ++j) hs[j] = 0.0f;
    }
    float cumd = 0.0f;
    __bf16* yC = yb + ((size_t)b * 1024 + c * CHUNK_) * 256 + dg * 128 + tid;

    __syncthreads();
#pragma unroll 2
    for (int tt = 0; tt < CHUNK_; ++tt) {
        const float* dtr = dts + tt * 8;
        float4 dt0 = *(const float4*)(dtr);
        float4 dt1 = *(const float4*)(dtr + 4);
        float dtv = dtbd;
        dtv = fmaf(dt0.x, dtwc[0], dtv); dtv = fmaf(dt0.y, dtwc[1], dtv);
        dtv = fmaf(dt0.z, dtwc[2], dtv); dtv = fmaf(dt0.w, dtwc[3], dtv);
        dtv = fmaf(dt1.x, dtwc[4], dtv); dtv = fmaf(dt1.y, dtwc[5], dtv);
        dtv = fmaf(dt1.z, dtwc[6], dtv); dtv = fmaf(dt1.w, dtwc[7], dtv);
        float delta_t = softplusf_(dtv);
        float u = (float)xcs[tt * 128 + tid];
        float du = delta_t * u;
        const float* bcr = bc + tt * 32;
        if (!FINAL) cumd += delta_t;
        float ys = 0.0f;
#pragma unroll
        for (int jj = 0; jj < 4; ++jj) {
            float4 Bv = *(const float4*)(bcr + jj * 4);
            float4 Cv;
            if (FINAL) Cv = *(const float4*)(bcr + 16 + jj * 4);
#pragma unroll
            for (int j = 0; j < 4; ++j) {
                int s = jj * 4 + j;
                float dA = fexp2_(delta_t * aa[s]);
                hs[s] = fmaf(dA, hs[s], du * ((const float*)&Bv)[j]);
                if (FINAL) ys = fmaf(hs[s], ((const float*)&Cv)[j], ys);
            }
        }
        if (FINAL) {
            float yv = fmaf(u, Dpd, ys);
            yv = fmaf(0.7f, yv, 0.3f * u);
            yC[(size_t)tt * 256] = (__bf16)yv;
        }
    }
    if (!FINAL) {
#pragma unroll
        for (int jj = 0; jj < 4; ++jj) {
            float4 pv, sv;
            pv.x = fexp2_(aa[jj * 4 + 0] * cumd);
            pv.y = fexp2_(aa[jj * 4 + 1] * cumd);
            pv.z = fexp2_(aa[jj * 4 + 2] * cumd);
            pv.w = fexp2_(aa[jj * 4 + 3] * cumd);
            sv.x = hs[jj * 4 + 0]; sv.y = hs[jj * 4 + 1];
            sv.z = hs[jj * 4 + 2]; sv.w = hs[jj * 4 + 3];
            *(float4*)(P + psIdx + jj * 4) = pv;
            *(float4*)(S + psIdx + jj * 4) = sv;
        }
    }
}

// ---------------- combine chunk aggregates: H_{c+1} = P_c*H_c + S_c --------------
__global__ __launch_bounds__(256) void k_scan_combine(float* __restrict__ P,
        const float* __restrict__ S) {
    int idx = blockIdx.x * 256 + threadIdx.x;
    int b = idx >> 12, rem = idx & 4095;
    float h = 0.0f;
#pragma unroll
    for (int c = 0; c < NCH_; ++c) {
        size_t base = ((size_t)(b * NCH_ + c)) * 4096 + rem;
        float p = P[base];
        float s = S[base];
        P[base] = h;
        h = fmaf(p, h, s);
    }
}

// ---------------- final LN + classifier (sums 32 gemm2-block partials) -----------
__global__ __launch_bounds__(128) void k_head(const float* __restrict__ pool2,
        const float* __restrict__ nw, const float* __restrict__ nb,
        const float* __restrict__ cw, const float* __restrict__ cb,
        float* __restrict__ out) {
    __shared__ float zs[128];
    __shared__ float red[128];
    int b = blockIdx.x, m = threadIdx.x;
    float v = 0.0f;
#pragma unroll 8
    for (int i = 0; i < 32; ++i) v += pool2[(size_t)(b * 32 + i) * 128 + m];
    v *= (1.0f / 1024.0f);
    red[m] = v;
    __syncthreads();
    for (int off = 64; off; off >>= 1) {
        if (m < off) red[m] += red[m + off];
        __syncthreads();
    }
    float mean = red[0] * (1.0f / 128.0f);
    __syncthreads();
    float dv = v - mean;
    red[m] = dv * dv;
    __syncthreads();
    for (int off = 64; off; off >>= 1) {
        if (m < off) red[m] += red[m + off];
        __syncthreads();
    }
    float rstd = rsqrtf(red[0] * (1.0f / 128.0f) + 1e-5f);
    zs[m] = dv * rstd * nw[m] + nb[m];
    __syncthreads();
    if (m < NC_) {
        float acc = cb[m];
#pragma unroll 8
        for (int k = 0; k < 128; ++k) acc = fmaf(zs[k], cw[k * 10 + m], acc);
        out[b * 10 + m] = acc;
    }
}

extern "C" void kernel_launch(void* const* d_in, const int* in_sizes, int n_in,
                              void* d_out, int out_size, void* d_ws, size_t ws_size,
                              hipStream_t stream) {
    const float* x    = (const float*)d_in[0];
    const float* Win  = (const float*)d_in[1];
    const float* bin  = (const float*)d_in[2];
    const float* lnw  = (const float*)d_in[3];
    const float* lnb  = (const float*)d_in[4];
    const float* ipw  = (const float*)d_in[5];
    const float* cw   = (const float*)d_in[6];
    const float* cb   = (const float*)d_in[7];
    const float* xpw  = (const float*)d_in[8];
    const float* dtw  = (const float*)d_in[9];
    const float* dtb  = (const float*)d_in[10];
    const float* Alog = (const float*)d_in[11];
    const float* Dp   = (const float*)d_in[12];
    const float* opw  = (const float*)d_in[13];
    const float* opb  = (const float*)d_in[14];
    const float* nw   = (const float*)d_in[15];
    const float* nb   = (const float*)d_in[16];
    const float* clw  = (const float*)d_in[17];
    const float* clb  = (const float*)d_in[18];

    // f32-slot offsets (all non-overlapping in time):
    //   h        [0,        4194304)
    //   P        [4194304,  8388608)   (zb bf16 aliases first half; zb consumed
    //                                   by gemm1 before scanA writes P)
    //   xinb bf16[8388608,  12582912)
    //   sgb  bf16[12582912, 16777216)
    //   xcb  bf16[16777216, 20971520)
    //   projall  [20971520, 22020096)  T*64 bf16
    //   yb bf16  [25690112, 29884416)
    //   wt1      [29917184, 30048256)
    //   wt2      [30048256, 30113792)
    //   wcat     [30113792, 30146560)
    //   Sb       [30310400, 34504704)
    //   pool2    [34504704, 34635776)  1024*128 f32
    float* ws = (float*)d_ws;
    float*  h       = ws;
    float*  P       = ws + 4194304;
    __bf16* zb      = (__bf16*)(ws + 4194304);
    __bf16* xinb    = (__bf16*)(ws + 8388608);
    __bf16* sgb     = (__bf16*)(ws + 12582912);
    __bf16* xcb     = (__bf16*)(ws + 16777216);
    __bf16* projall = (__bf16*)(ws + 20971520);
    __bf16* yb      = (__bf16*)(ws + 25690112);
    __bf16* wt1     = (__bf16*)(ws + 29917184);
    __bf16* wt2     = (__bf16*)(ws + 30048256);
    __bf16* wcat    = (__bf16*)(ws + 30113792);
    float*  Sb      = ws + 30310400;
    float*  pool2   = ws + 34504704;

    k_prep<<<1024, 256, 0, stream>>>(ipw, opw, xpw, wt1, wt2, wcat);
    k_embed_ln<<<T_ / 4, 256, 0, stream>>>(x, Win, bin, lnw, lnb, h, zb);
    for (int lay = 0; lay < 4; ++lay) {
        k_gemm_mfma<64, 128, 512, 0, false, false, false><<<dim3(T_ / 64, 4), 256, 0, stream>>>(
            zb, nullptr, wt1 + (size_t)lay * 65536, nullptr, nullptr, xinb,
            nullptr, nullptr, sgb, nullptr);
        k_convproj<<<T_ / 16, 256, 0, stream>>>(xinb, cw + lay * 1024, cb + lay * 256,
            wcat + (size_t)lay * 16384, xcb, projall);
        k_scan_chunk<false><<<dim3(2, NCH_, B_), 128, 0, stream>>>(projall, xcb,
            dtw + lay * 2048, dtb + lay * 256, Alog + lay * 4096, Dp + lay * 256,
            P, Sb, yb);
        k_scan_combine<<<B_ * 4096 / 256, 256, 0, stream>>>(P, Sb);
        k_scan_chunk<true><<<dim3(2, NCH_, B_), 128, 0, stream>>>(projall, xcb,
            dtw + lay * 2048, dtb + lay * 256, Alog + lay * 4096, Dp + lay * 256,
            P, Sb, yb);
        if (lay < 3) {
            k_gemm_mfma<32, 256, 128, 2, true, true, false><<<dim3(T_ / 32, 1), 256, 0, stream>>>(
                yb, sgb, wt2 + (size_t)lay * 32768, opb + lay * 128, h, nullptr,
                lnw + (lay + 1) * 128, lnb + (lay + 1) * 128, zb, nullptr);
        } else {
            k_gemm_mfma<32, 256, 128, 2, true, false, true><<<dim3(T_ / 32, 1), 256, 0, stream>>>(
                yb, sgb, wt2 + (size_t)lay * 32768, opb + lay * 128, h, nullptr,
                nullptr, nullptr, nullptr, pool2);
        }
    }
    k_head<<<32, 128, 0, stream>>>(pool2, nw, nb, clw, clb, (float*)d_out);
}

// Round 17
// 608.231 us; speedup vs baseline: 1.2324x; 1.2324x over previous
//
#include <hip/hip_runtime.h>
#include <math.h>

// Problem constants
#define B_  32
#define L_  1024
#define T_  (B_ * L_)       // 32768 tokens
#define DM_ 128
#define DI_ 256
#define DS_ 16
#define DC_ 4
#define DR_ 8
#define NC_ 10
#define CHUNK_ 32
#define NCH_  (L_ / CHUNK_)   // 32 chunks
#define PSTR_ 64              // projall row stride (bf16): 8 dt | 16 B | 16 C | pad

typedef __bf16 bf16x8 __attribute__((ext_vector_type(8)));
typedef __bf16 bf16x4 __attribute__((ext_vector_type(4)));
typedef __bf16 bf16x2 __attribute__((ext_vector_type(2)));
typedef float f32x4 __attribute__((ext_vector_type(4)));

__device__ __forceinline__ float sigmoidf_(float x) { return 1.0f / (1.0f + __expf(-x)); }
__device__ __forceinline__ float siluf_(float x)    { return x * sigmoidf_(x); }
__device__ __forceinline__ float softplusf_(float x) {
    return (x > 15.0f) ? x : __logf(1.0f + __expf(x));
}
__device__ __forceinline__ float fexp2_(float x) { return __builtin_amdgcn_exp2f(x); }

// async 16B global->LDS (gfx950). dest = wave-uniform base + lane*16.
__device__ __forceinline__ void gload_lds16(const __bf16* g, __bf16* l) {
    __builtin_amdgcn_global_load_lds(
        (const __attribute__((address_space(1))) void*)g,
        (__attribute__((address_space(3))) void*)l, 16, 0, 0);
}

// Stage an R x 64 bf16 tile (row stride `stride`, col offset k0) into LDS with
// XOR-swizzle baked in: LDS (row, sw) holds source (row, sw ^ (row&7)).
template<int R>
__device__ __forceinline__ void stage_async(const __bf16* __restrict__ src,
        __bf16* lds, int k0, int stride, int wid, int lane) {
    constexpr int NI = R / 32;
#pragma unroll
    for (int j = 0; j < NI; ++j) {
        int s0 = (wid * NI + j) * 64;
        int s = s0 + lane;
        int row = s >> 3, sw = s & 7;
        int slot = sw ^ (row & 7);
        gload_lds16(src + (size_t)row * stride + k0 + slot * 8, lds + (size_t)s0 * 8);
    }
}

// ---------------- fused embed + layernorm (layer 0) -------------------------------
__global__ __launch_bounds__(256) void k_embed_ln(const float* __restrict__ x,
        const float* __restrict__ Win, const float* __restrict__ bin,
        const float* __restrict__ lnw, const float* __restrict__ lnb,
        float* __restrict__ h, __bf16* __restrict__ z) {
    int wid = threadIdx.x >> 6, lane = threadIdx.x & 63;
    int t = blockIdx.x * 4 + wid;
    int b = t >> 10, l = t & 1023;
    const float* xb = x + (size_t)b * 3 * 1024 + l;
    float x0 = xb[0], x1 = xb[1024], x2 = xb[2048];
    int m = lane * 2;
    float2 v;
    v.x = bin[m]     + x0 * Win[m]     + x1 * Win[128 + m]     + x2 * Win[256 + m];
    v.y = bin[m + 1] + x0 * Win[m + 1] + x1 * Win[128 + m + 1] + x2 * Win[256 + m + 1];
    *(float2*)(h + (size_t)t * 128 + m) = v;
    float s = v.x + v.y, sq = v.x * v.x + v.y * v.y;
#pragma unroll
    for (int off = 1; off < 64; off <<= 1) {
        s += __shfl_xor(s, off);
        sq += __shfl_xor(sq, off);
    }
    float mean = s * (1.0f / 128.0f);
    float var = sq * (1.0f / 128.0f) - mean * mean;
    float rstd = rsqrtf(var + 1e-5f);
    float2 wv = *(const float2*)(lnw + m);
    float2 bv = *(const float2*)(lnb + m);
    bf16x2 o;
    o.x = (__bf16)((v.x - mean) * rstd * wv.x + bv.x);
    o.y = (__bf16)((v.y - mean) * rstd * wv.y + bv.y);
    *(bf16x2*)(z + (size_t)t * 128 + m) = o;
}

// ---------------- merged weight prep ----------------------------------------------
// wt1[lay][n<512][k<128]; wt2[lay][n<128][k<256]; wcat[lay][n<64][k<256]
// (wcat n<40 = xpw col n transposed; else 0).
__global__ __launch_bounds__(256) void k_prep(const float* __restrict__ ipw,
        const float* __restrict__ opw, const float* __restrict__ xpw,
        __bf16* __restrict__ wt1, __bf16* __restrict__ wt2,
        __bf16* __restrict__ wcat) {
    int blk = blockIdx.x;              // 0..1023
    int tid = threadIdx.x;
    int i = blk * 256 + tid;
    {
        int lay = i >> 16, rem = i & 65535, n = rem >> 7, k = rem & 127;
        wt1[i] = (__bf16)ipw[lay * 65536 + k * 512 + n];
    }
    if (i < 131072) {
        int lay = i >> 15, rem = i & 32767, n = rem >> 8, k = rem & 255;
        wt2[i] = (__bf16)opw[lay * 32768 + k * 128 + n];
    }
    if (blk < 256) {
        int lay = blk >> 6, n = blk & 63;
        int k = tid;
        float v = (n < 40) ? xpw[lay * 10240 + k * 40 + n] : 0.0f;
        wcat[(size_t)blk * 256 + k] = (__bf16)v;
    }
}

// ---------------- bf16 MFMA GEMM, BM x 128 tile, BK=64 ---------------------------
// MODE 0 (gemm1, N=512): col<256 -> Cb=xinb raw bf16 (stride 256);
//                        col>=256 -> Zb=sgb silu(v) bf16 (stride 256).
// MODE 1 (xproj, N=128): col<40 raw bf16 at stride PSTR_      [-> projall]
// MODE 2 (gemm2, N=128): Cf += acc + bias (f32); GATE A = y*sg (sg pre-silu'd).
//   WLN: fused LayerNorm -> next zb.   POOL: column-sums -> Pool[bm][128].
template<int BM, int K, int N, int MODE, bool GATE, bool WLN, bool POOL>
__global__ __launch_bounds__(256) void k_gemm_mfma(
        const __bf16* __restrict__ A, const __bf16* __restrict__ G,
        const __bf16* __restrict__ Wt, const float* __restrict__ bias,
        float* __restrict__ Cf, __bf16* __restrict__ Cb,
        const float* __restrict__ lnw, const float* __restrict__ lnb,
        __bf16* __restrict__ Zb, float* __restrict__ Pool) {
    static_assert(!GATE || BM == 32, "GATE staging assumes BM=32");
    static_assert(!WLN || (MODE == 2 && BM == 32 && N == 128), "WLN geometry");
    static_assert(!POOL || (MODE == 2 && BM == 32 && N == 128), "POOL geometry");
    __shared__ __bf16 As[BM * 64];
    __shared__ __bf16 Bs[128 * 64];
    __shared__ float red_s[WLN ? 4 : 1][WLN ? 32 : 1];
    __shared__ float red_q[WLN ? 4 : 1][WLN ? 32 : 1];
    int tid = threadIdx.x;
    int bm = blockIdx.x, bn = blockIdx.y;
    int lane = tid & 63, wid = tid >> 6;
    int lr = lane & 15, lg = lane >> 4;
    constexpr int MF = BM / 16;

    f32x4 acc[MF][2] = {};
    const __bf16* Asrc = A + (size_t)(bm * BM) * K;
    const __bf16* Bsrc = Wt + (size_t)(bn * 128) * K;

    for (int k0 = 0; k0 < K; k0 += 64) {
        if (GATE) {
            int row = tid >> 3, slot = tid & 7;
            int m = bm * BM + row;
            bf16x8 yv = *(const bf16x8*)(A + (size_t)m * K + k0 + slot * 8);
            bf16x8 gv = *(const bf16x8*)(G + (size_t)m * 256 + k0 + slot * 8);
            bf16x8 v;
#pragma unroll
            for (int j = 0; j < 8; ++j)
                v[j] = (__bf16)((float)yv[j] * (float)gv[j]);
            *(bf16x8*)(As + row * 64 + ((slot ^ (row & 7)) * 8)) = v;
        } else {
            stage_async<BM>(Asrc, As, k0, K, wid, lane);
        }
        stage_async<128>(Bsrc, Bs, k0, K, wid, lane);
        __syncthreads();
#pragma unroll
        for (int ks = 0; ks < 2; ++ks) {
            int slotbase = ks * 4 + lg;
            bf16x8 af[MF], bfr[2];
#pragma unroll
            for (int m = 0; m < MF; ++m) {
                int row = m * 16 + lr;
                af[m] = *(const bf16x8*)(As + row * 64 + ((slotbase ^ (row & 7)) * 8));
            }
#pragma unroll
            for (int n = 0; n < 2; ++n) {
                int rn = wid * 32 + n * 16 + lr;
                bfr[n] = *(const bf16x8*)(Bs + rn * 64 + ((slotbase ^ (rn & 7)) * 8));
            }
#pragma unroll
            for (int m = 0; m < MF; ++m)
#pragma unroll
                for (int n = 0; n < 2; ++n)
                    acc[m][n] = __builtin_amdgcn_mfma_f32_16x16x32_bf16(
                        af[m], bfr[n], acc[m][n], 0, 0, 0);
        }
        __syncthreads();
    }
    // ---- epilogue: D[row=(lane>>4)*4+reg][col=lane&15] ----
    float vv[MF][2][4];
#pragma unroll
    for (int m = 0; m < MF; ++m) {
#pragma unroll
        for (int n = 0; n < 2; ++n) {
            int col = bn * 128 + wid * 32 + n * 16 + lr;
            float bv = (MODE == 2) ? bias[col] : 0.0f;
#pragma unroll
            for (int rg = 0; rg < 4; ++rg) {
                int row = bm * BM + m * 16 + lg * 4 + rg;
                float v = acc[m][n][rg];
                if (MODE == 0) {
                    if (col < 256)
                        Cb[(size_t)row * 256 + col] = (__bf16)v;
                    else
                        Zb[(size_t)row * 256 + (col - 256)] = (__bf16)siluf_(v);
                } else if (MODE == 1) {
                    if (col < 40)
                        Cb[(size_t)row * PSTR_ + col] = (__bf16)v;
                } else {
                    float* cp = Cf + (size_t)row * N + col;
                    v += *cp + bv;
                    *cp = v;
                    vv[m][n][rg] = v;
                }
            }
        }
    }
    if (WLN) {
        float ps[MF][4], pq[MF][4];
#pragma unroll
        for (int m = 0; m < MF; ++m)
#pragma unroll
            for (int rg = 0; rg < 4; ++rg) {
                float a = vv[m][0][rg], bv2 = vv[m][1][rg];
                ps[m][rg] = a + bv2;
                pq[m][rg] = a * a + bv2 * bv2;
            }
#pragma unroll
        for (int off = 1; off < 16; off <<= 1) {
#pragma unroll
            for (int m = 0; m < MF; ++m)
#pragma unroll
                for (int rg = 0; rg < 4; ++rg) {
                    ps[m][rg] += __shfl_xor(ps[m][rg], off);
                    pq[m][rg] += __shfl_xor(pq[m][rg], off);
                }
        }
        if (lr == 0) {
#pragma unroll
            for (int m = 0; m < MF; ++m)
#pragma unroll
                for (int rg = 0; rg < 4; ++rg) {
                    int rl = m * 16 + lg * 4 + rg;
                    red_s[wid][rl] = ps[m][rg];
                    red_q[wid][rl] = pq[m][rg];
                }
        }
        __syncthreads();
#pragma unroll
        for (int m = 0; m < MF; ++m)
#pragma unroll
            for (int rg = 0; rg < 4; ++rg) {
                int rl = m * 16 + lg * 4 + rg;
                float s = red_s[0][rl] + red_s[1][rl] + red_s[2][rl] + red_s[3][rl];
                float q = red_q[0][rl] + red_q[1][rl] + red_q[2][rl] + red_q[3][rl];
                float mean = s * (1.0f / 128.0f);
                float var = q * (1.0f / 128.0f) - mean * mean;
                float rstd = rsqrtf(var + 1e-5f);
#pragma unroll
                for (int n = 0; n < 2; ++n) {
                    int col = wid * 32 + n * 16 + lr;
                    float z = (vv[m][n][rg] - mean) * rstd * lnw[col] + lnb[col];
                    Zb[(size_t)(bm * BM + rl) * 128 + col] = (__bf16)z;
                }
            }
    }
    if (POOL) {
#pragma unroll
        for (int n = 0; n < 2; ++n) {
            float s = 0.0f;
#pragma unroll
            for (int m = 0; m < MF; ++m)
#pragma unroll
                for (int rg = 0; rg < 4; ++rg) s += vv[m][n][rg];
            s += __shfl_xor(s, 16);
            s += __shfl_xor(s, 32);      // summed over all 32 rows
            if (lg == 0)
                Pool[(size_t)bm * 128 + wid * 32 + n * 16 + lr] = s;
        }
    }
}

// ---------------- causal depthwise conv (width 4) + SiLU, vectorized -------------
__global__ __launch_bounds__(256) void k_conv(const __bf16* __restrict__ xinb,
        const float* __restrict__ cw, const float* __restrict__ cb,
        __bf16* __restrict__ xcb) {
    int t = blockIdx.x * 4 + (threadIdx.x >> 6);
    int d0 = (threadIdx.x & 63) * 4;
    int l = t & 1023;
    const __bf16* xp = xinb + (size_t)t * 256 + d0;
    float4 wv[4];
#pragma unroll
    for (int j = 0; j < 4; ++j) wv[j] = *(const float4*)(cw + (d0 + j) * 4);
    float acc[4] = {cb[d0], cb[d0 + 1], cb[d0 + 2], cb[d0 + 3]};
#pragma unroll
    for (int k = 0; k < 4; ++k) {
        int back = 3 - k;
        if (l >= back) {
            bf16x4 v = *(const bf16x4*)(xp - back * 256);
#pragma unroll
            for (int j = 0; j < 4; ++j)
                acc[j] = fmaf((float)v[j], ((const float*)&wv[j])[k], acc[j]);
        }
    }
    bf16x4 o;
#pragma unroll
    for (int j = 0; j < 4; ++j) o[j] = (__bf16)siluf_(acc[j]);
    *(bf16x4*)(xcb + (size_t)t * 256 + d0) = o;
}

// ---------------- chunk-parallel SSM scan: one thread per d ----------------------
// projall rows: [0..7]=dt, [8..23]=B, [24..39]=C (bf16, stride PSTR_=64).
// delta computed inline: softplus(dt . dtw[:,d] + dtb[d]).
template<bool FINAL>
__global__ __launch_bounds__(128) void k_scan_chunk(
        const __bf16* __restrict__ projall, const __bf16* __restrict__ xcb,
        const float* __restrict__ dtw, const float* __restrict__ dtb,
        const float* __restrict__ Alog, const float* __restrict__ Dp,
        float* __restrict__ P, float* __restrict__ S,
        __bf16* __restrict__ yb) {
    __shared__ __bf16 xcs[CHUNK_ * 128];        // 8 KB
    __shared__ float bc[CHUNK_ * 32];           // 4 KB
    __shared__ float dts[CHUNK_ * 8];           // 1 KB
    int b = blockIdx.z, c = blockIdx.y, dg = blockIdx.x;   // dg in {0,1}
    int tid = threadIdx.x;                      // 0..127
    int d = dg * 128 + tid;

    const __bf16* projC = projall + ((size_t)b * 1024 + c * CHUNK_) * PSTR_;
    const __bf16* xcC   = xcb + ((size_t)b * 1024 + c * CHUNK_) * 256 + dg * 128;

#pragma unroll
    for (int r = 0; r < (CHUNK_ * 16) / 128; ++r) {
        int item = r * 128 + tid;
        int t = item >> 4, o8 = (item & 15) * 8;
        *(bf16x8*)(xcs + t * 128 + o8) = *(const bf16x8*)(xcC + (size_t)t * 256 + o8);
    }
    {
        int t = tid >> 2, g8 = (tid & 3) * 8;
        bf16x8 v = *(const bf16x8*)(projC + (size_t)t * PSTR_ + 8 + g8);
        float4 f0 = {(float)v[0], (float)v[1], (float)v[2], (float)v[3]};
        float4 f1 = {(float)v[4], (float)v[5], (float)v[6], (float)v[7]};
        *(float4*)(bc + t * 32 + g8)     = f0;
        *(float4*)(bc + t * 32 + g8 + 4) = f1;
    }
    if (tid < CHUNK_) {
        bf16x8 v = *(const bf16x8*)(projC + (size_t)tid * PSTR_);
#pragma unroll
        for (int j = 0; j < 8; ++j) dts[tid * 8 + j] = (float)v[j];
    }

    float dtwc[8];
#pragma unroll
    for (int r = 0; r < 8; ++r) dtwc[r] = dtw[r * 256 + d];
    float dtbd = dtb[d];
    float aa[16], hs[16];
#pragma unroll
    for (int jj = 0; jj < 4; ++jj) {
        float4 av = *(const float4*)(Alog + (size_t)d * 16 + jj * 4);
        aa[jj * 4 + 0] = -__expf(av.x) * 1.44269504088896f;
        aa[jj * 4 + 1] = -__expf(av.y) * 1.44269504088896f;
        aa[jj * 4 + 2] = -__expf(av.z) * 1.44269504088896f;
        aa[jj * 4 + 3] = -__expf(av.w) * 1.44269504088896f;
    }
    float Dpd = Dp[d];
    size_t psIdx = ((size_t)(b * NCH_ + c)) * 4096 + (size_t)d * 16;
    if (FINAL) {
#pragma unroll
        for (int jj = 0; jj < 4; ++jj) {
            float4 h0 = *(const float4*)(P + psIdx + jj * 4);
            hs[jj * 4 + 0] = h0.x; hs[jj * 4 + 1] = h0.y;
            hs[jj * 4 + 2] = h0.z; hs[jj * 4 + 3] = h0.w;
        }
    } else {
#pragma unroll
        for (int j = 0; j < 16; ++j) hs[j] = 0.0f;
    }
    float cumd = 0.0f;
    __bf16* yC = yb + ((size_t)b * 1024 + c * CHUNK_) * 256 + dg * 128 + tid;

    __syncthreads();
#pragma unroll 2
    for (int tt = 0; tt < CHUNK_; ++tt) {
        const float* dtr = dts + tt * 8;
        float4 dt0 = *(const float4*)(dtr);
        float4 dt1 = *(const float4*)(dtr + 4);
        float dtv = dtbd;
        dtv = fmaf(dt0.x, dtwc[0], dtv); dtv = fmaf(dt0.y, dtwc[1], dtv);
        dtv = fmaf(dt0.z, dtwc[2], dtv); dtv = fmaf(dt0.w, dtwc[3], dtv);
        dtv = fmaf(dt1.x, dtwc[4], dtv); dtv = fmaf(dt1.y, dtwc[5], dtv);
        dtv = fmaf(dt1.z, dtwc[6], dtv); dtv = fmaf(dt1.w, dtwc[7], dtv);
        float delta_t = softplusf_(dtv);
        float u = (float)xcs[tt * 128 + tid];
        float du = delta_t * u;
        const float* bcr = bc + tt * 32;
        if (!FINAL) cumd += delta_t;
        float ys = 0.0f;
#pragma unroll
        for (int jj = 0; jj < 4; ++jj) {
            float4 Bv = *(const float4*)(bcr + jj * 4);
            float4 Cv;
            if (FINAL) Cv = *(const float4*)(bcr + 16 + jj * 4);
#pragma unroll
            for (int j = 0; j < 4; ++j) {
                int s = jj * 4 + j;
                float dA = fexp2_(delta_t * aa[s]);
                hs[s] = fmaf(dA, hs[s], du * ((const float*)&Bv)[j]);
                if (FINAL) ys = fmaf(hs[s], ((const float*)&Cv)[j], ys);
            }
        }
        if (FINAL) {
            float yv = fmaf(u, Dpd, ys);
            yv = fmaf(0.7f, yv, 0.3f * u);
            yC[(size_t)tt * 256] = (__bf16)yv;
        }
    }
    if (!FINAL) {
#pragma unroll
        for (int jj = 0; jj < 4; ++jj) {
            float4 pv, sv;
            pv.x = fexp2_(aa[jj * 4 + 0] * cumd);
            pv.y = fexp2_(aa[jj * 4 + 1] * cumd);
            pv.z = fexp2_(aa[jj * 4 + 2] * cumd);
            pv.w = fexp2_(aa[jj * 4 + 3] * cumd);
            sv.x = hs[jj * 4 + 0]; sv.y = hs[jj * 4 + 1];
            sv.z = hs[jj * 4 + 2]; sv.w = hs[jj * 4 + 3];
            *(float4*)(P + psIdx + jj * 4) = pv;
            *(float4*)(S + psIdx + jj * 4) = sv;
        }
    }
}

// ---------------- combine chunk aggregates: H_{c+1} = P_c*H_c + S_c --------------
__global__ __launch_bounds__(256) void k_scan_combine(float* __restrict__ P,
        const float* __restrict__ S) {
    int idx = blockIdx.x * 256 + threadIdx.x;
    int b = idx >> 12, rem = idx & 4095;
    float h = 0.0f;
#pragma unroll
    for (int c = 0; c < NCH_; ++c) {
        size_t base = ((size_t)(b * NCH_ + c)) * 4096 + rem;
        float p = P[base];
        float s = S[base];
        P[base] = h;
        h = fmaf(p, h, s);
    }
}

// ---------------- final LN + classifier (sums 32 gemm2-block partials) -----------
__global__ __launch_bounds__(128) void k_head(const float* __restrict__ pool2,
        const float* __restrict__ nw, const float* __restrict__ nb,
        const float* __restrict__ cw, const float* __restrict__ cb,
        float* __restrict__ out) {
    __shared__ float zs[128];
    __shared__ float red[128];
    int b = blockIdx.x, m = threadIdx.x;
    float v = 0.0f;
#pragma unroll 8
    for (int i = 0; i < 32; ++i) v += pool2[(size_t)(b * 32 + i) * 128 + m];
    v *= (1.0f / 1024.0f);
    red[m] = v;
    __syncthreads();
    for (int off = 64; off; off >>= 1) {
        if (m < off) red[m] += red[m + off];
        __syncthreads();
    }
    float mean = red[0] * (1.0f / 128.0f);
    __syncthreads();
    float dv = v - mean;
    red[m] = dv * dv;
    __syncthreads();
    for (int off = 64; off; off >>= 1) {
        if (m < off) red[m] += red[m + off];
        __syncthreads();
    }
    float rstd = rsqrtf(red[0] * (1.0f / 128.0f) + 1e-5f);
    zs[m] = dv * rstd * nw[m] + nb[m];
    __syncthreads();
    if (m < NC_) {
        float acc = cb[m];
#pragma unroll 8
        for (int k = 0; k < 128; ++k) acc = fmaf(zs[k], cw[k * 10 + m], acc);
        out[b * 10 + m] = acc;
    }
}

extern "C" void kernel_launch(void* const* d_in, const int* in_sizes, int n_in,
                              void* d_out, int out_size, void* d_ws, size_t ws_size,
                              hipStream_t stream) {
    const float* x    = (const float*)d_in[0];
    const float* Win  = (const float*)d_in[1];
    const float* bin  = (const float*)d_in[2];
    const float* lnw  = (const float*)d_in[3];
    const float* lnb  = (const float*)d_in[4];
    const float* ipw  = (const float*)d_in[5];
    const float* cw   = (const float*)d_in[6];
    const float* cb   = (const float*)d_in[7];
    const float* xpw  = (const float*)d_in[8];
    const float* dtw  = (const float*)d_in[9];
    const float* dtb  = (const float*)d_in[10];
    const float* Alog = (const float*)d_in[11];
    const float* Dp   = (const float*)d_in[12];
    const float* opw  = (const float*)d_in[13];
    const float* opb  = (const float*)d_in[14];
    const float* nw   = (const float*)d_in[15];
    const float* nb   = (const float*)d_in[16];
    const float* clw  = (const float*)d_in[17];
    const float* clb  = (const float*)d_in[18];

    // f32-slot offsets (all non-overlapping in time):
    //   h        [0,        4194304)
    //   P        [4194304,  8388608)   (zb bf16 aliases first half; zb consumed
    //                                   by gemm1 before scanA writes P)
    //   xinb bf16[8388608,  12582912)
    //   sgb  bf16[12582912, 16777216)
    //   xcb  bf16[16777216, 20971520)
    //   projall  [20971520, 22020096)  T*64 bf16
    //   yb bf16  [25690112, 29884416)
    //   wt1      [29917184, 30048256)
    //   wt2      [30048256, 30113792)
    //   wcat     [30113792, 30146560)
    //   Sb       [30310400, 34504704)
    //   pool2    [34504704, 34635776)  1024*128 f32
    float* ws = (float*)d_ws;
    float*  h       = ws;
    float*  P       = ws + 4194304;
    __bf16* zb      = (__bf16*)(ws + 4194304);
    __bf16* xinb    = (__bf16*)(ws + 8388608);
    __bf16* sgb     = (__bf16*)(ws + 12582912);
    __bf16* xcb     = (__bf16*)(ws + 16777216);
    __bf16* projall = (__bf16*)(ws + 20971520);
    __bf16* yb      = (__bf16*)(ws + 25690112);
    __bf16* wt1     = (__bf16*)(ws + 29917184);
    __bf16* wt2     = (__bf16*)(ws + 30048256);
    __bf16* wcat    = (__bf16*)(ws + 30113792);
    float*  Sb      = ws + 30310400;
    float*  pool2   = ws + 34504704;

    k_prep<<<1024, 256, 0, stream>>>(ipw, opw, xpw, wt1, wt2, wcat);
    k_embed_ln<<<T_ / 4, 256, 0, stream>>>(x, Win, bin, lnw, lnb, h, zb);
    for (int lay = 0; lay < 4; ++lay) {
        k_gemm_mfma<64, 128, 512, 0, false, false, false><<<dim3(T_ / 64, 4), 256, 0, stream>>>(
            zb, nullptr, wt1 + (size_t)lay * 65536, nullptr, nullptr, xinb,
            nullptr, nullptr, sgb, nullptr);
        k_conv<<<T_ / 4, 256, 0, stream>>>(xinb, cw + lay * 1024, cb + lay * 256, xcb);
        k_gemm_mfma<64, 256, 128, 1, false, false, false><<<dim3(T_ / 64, 1), 256, 0, stream>>>(
            xcb, nullptr, wcat + (size_t)lay * 16384, nullptr, nullptr, projall,
            nullptr, nullptr, nullptr, nullptr);
        k_scan_chunk<false><<<dim3(2, NCH_, B_), 128, 0, stream>>>(projall, xcb,
            dtw + lay * 2048, dtb + lay * 256, Alog + lay * 4096, Dp + lay * 256,
            P, Sb, yb);
        k_scan_combine<<<B_ * 4096 / 256, 256, 0, stream>>>(P, Sb);
        k_scan_chunk<true><<<dim3(2, NCH_, B_), 128, 0, stream>>>(projall, xcb,
            dtw + lay * 2048, dtb + lay * 256, Alog + lay * 4096, Dp + lay * 256,
            P, Sb, yb);
        if (lay < 3) {
            k_gemm_mfma<32, 256, 128, 2, true, true, false><<<dim3(T_ / 32, 1), 256, 0, stream>>>(
                yb, sgb, wt2 + (size_t)lay * 32768, opb + lay * 128, h, nullptr,
                lnw + (lay + 1) * 128, lnb + (lay + 1) * 128, zb, nullptr);
        } else {
            k_gemm_mfma<32, 256, 128, 2, true, false, true><<<dim3(T_ / 32, 1), 256, 0, stream>>>(
                yb, sgb, wt2 + (size_t)lay * 32768, opb + lay * 128, h, nullptr,
                nullptr, nullptr, nullptr, pool2);
        }
    }
    k_head<<<32, 128, 0, stream>>>(pool2, nw, nb, clw, clb, (float*)d_out);
}

// Round 18
// 590.149 us; speedup vs baseline: 1.2701x; 1.0306x over previous
//
#include <hip/hip_runtime.h>
#include <math.h>

// Problem constants
#define B_  32
#define L_  1024
#define T_  (B_ * L_)       // 32768 tokens
#define DM_ 128
#define DI_ 256
#define DS_ 16
#define DC_ 4
#define DR_ 8
#define NC_ 10
#define CHUNK_ 32
#define NCH_  (L_ / CHUNK_)   // 32 chunks
#define PSTR_ 64              // projall row stride (bf16): 8 dt | 16 B | 16 C | pad

typedef __bf16 bf16x8 __attribute__((ext_vector_type(8)));
typedef __bf16 bf16x4 __attribute__((ext_vector_type(4)));
typedef __bf16 bf16x2 __attribute__((ext_vector_type(2)));
typedef float f32x4 __attribute__((ext_vector_type(4)));

__device__ __forceinline__ float sigmoidf_(float x) { return 1.0f / (1.0f + __expf(-x)); }
__device__ __forceinline__ float siluf_(float x)    { return x * sigmoidf_(x); }
__device__ __forceinline__ float softplusf_(float x) {
    return (x > 15.0f) ? x : __logf(1.0f + __expf(x));
}
__device__ __forceinline__ float fexp2_(float x) { return __builtin_amdgcn_exp2f(x); }

// async 16B global->LDS (gfx950). dest = wave-uniform base + lane*16.
__device__ __forceinline__ void gload_lds16(const __bf16* g, __bf16* l) {
    __builtin_amdgcn_global_load_lds(
        (const __attribute__((address_space(1))) void*)g,
        (__attribute__((address_space(3))) void*)l, 16, 0, 0);
}

// Stage an R x 64 bf16 tile (row stride `stride`, col offset k0) into LDS with
// XOR-swizzle baked in: LDS (row, sw) holds source (row, sw ^ (row&7)).
template<int R>
__device__ __forceinline__ void stage_async(const __bf16* __restrict__ src,
        __bf16* lds, int k0, int stride, int wid, int lane) {
    constexpr int NI = R / 32;
#pragma unroll
    for (int j = 0; j < NI; ++j) {
        int s0 = (wid * NI + j) * 64;
        int s = s0 + lane;
        int row = s >> 3, sw = s & 7;
        int slot = sw ^ (row & 7);
        gload_lds16(src + (size_t)row * stride + k0 + slot * 8, lds + (size_t)s0 * 8);
    }
}

// ---------------- fused embed + layernorm (layer 0) -------------------------------
__global__ __launch_bounds__(256) void k_embed_ln(const float* __restrict__ x,
        const float* __restrict__ Win, const float* __restrict__ bin,
        const float* __restrict__ lnw, const float* __restrict__ lnb,
        float* __restrict__ h, __bf16* __restrict__ z) {
    int wid = threadIdx.x >> 6, lane = threadIdx.x & 63;
    int t = blockIdx.x * 4 + wid;
    int b = t >> 10, l = t & 1023;
    const float* xb = x + (size_t)b * 3 * 1024 + l;
    float x0 = xb[0], x1 = xb[1024], x2 = xb[2048];
    int m = lane * 2;
    float2 v;
    v.x = bin[m]     + x0 * Win[m]     + x1 * Win[128 + m]     + x2 * Win[256 + m];
    v.y = bin[m + 1] + x0 * Win[m + 1] + x1 * Win[128 + m + 1] + x2 * Win[256 + m + 1];
    *(float2*)(h + (size_t)t * 128 + m) = v;
    float s = v.x + v.y, sq = v.x * v.x + v.y * v.y;
#pragma unroll
    for (int off = 1; off < 64; off <<= 1) {
        s += __shfl_xor(s, off);
        sq += __shfl_xor(sq, off);
    }
    float mean = s * (1.0f / 128.0f);
    float var = sq * (1.0f / 128.0f) - mean * mean;
    float rstd = rsqrtf(var + 1e-5f);
    float2 wv = *(const float2*)(lnw + m);
    float2 bv = *(const float2*)(lnb + m);
    bf16x2 o;
    o.x = (__bf16)((v.x - mean) * rstd * wv.x + bv.x);
    o.y = (__bf16)((v.y - mean) * rstd * wv.y + bv.y);
    *(bf16x2*)(z + (size_t)t * 128 + m) = o;
}

// ---------------- merged weight prep ----------------------------------------------
// wt1[lay][n<512][k<128]; wt2[lay][n<128][k<256]; wcat[lay][n<64][k<256]
// (wcat n<40 = xpw col n transposed; else 0).
__global__ __launch_bounds__(256) void k_prep(const float* __restrict__ ipw,
        const float* __restrict__ opw, const float* __restrict__ xpw,
        __bf16* __restrict__ wt1, __bf16* __restrict__ wt2,
        __bf16* __restrict__ wcat) {
    int blk = blockIdx.x;              // 0..1023
    int tid = threadIdx.x;
    int i = blk * 256 + tid;
    {
        int lay = i >> 16, rem = i & 65535, n = rem >> 7, k = rem & 127;
        wt1[i] = (__bf16)ipw[lay * 65536 + k * 512 + n];
    }
    if (i < 131072) {
        int lay = i >> 15, rem = i & 32767, n = rem >> 8, k = rem & 255;
        wt2[i] = (__bf16)opw[lay * 32768 + k * 128 + n];
    }
    if (blk < 256) {
        int lay = blk >> 6, n = blk & 63;
        int k = tid;
        float v = (n < 40) ? xpw[lay * 10240 + k * 40 + n] : 0.0f;
        wcat[(size_t)blk * 256 + k] = (__bf16)v;
    }
}

// ---------------- bf16 MFMA GEMM, BM x 128 tile, BK=64 ---------------------------
// MODE 0 (gemm1, N=512): bn<2 -> Cb=xinb raw bf16; bn>=2 -> Zb=sgb silu(v).
//   Coalesced epilogue through LDS (reuses Bs).
// MODE 1 (xproj, N=128): cols<64 bf16 at stride PSTR_=64 (cols 40..63 pad junk).
//   Coalesced epilogue through LDS.
// MODE 2 (gemm2, N=128): Cf += acc + bias (f32); GATE A = y*sg (sg pre-silu'd).
//   WLN: fused LayerNorm -> next zb.   POOL: column-sums -> Pool[bm][128].
template<int BM, int K, int N, int MODE, bool GATE, bool WLN, bool POOL>
__global__ __launch_bounds__(256) void k_gemm_mfma(
        const __bf16* __restrict__ A, const __bf16* __restrict__ G,
        const __bf16* __restrict__ Wt, const float* __restrict__ bias,
        float* __restrict__ Cf, __bf16* __restrict__ Cb,
        const float* __restrict__ lnw, const float* __restrict__ lnb,
        __bf16* __restrict__ Zb, float* __restrict__ Pool) {
    static_assert(!GATE || BM == 32, "GATE staging assumes BM=32");
    static_assert(!WLN || (MODE == 2 && BM == 32 && N == 128), "WLN geometry");
    static_assert(!POOL || (MODE == 2 && BM == 32 && N == 128), "POOL geometry");
    __shared__ __bf16 As[BM * 64];
    __shared__ __bf16 Bs[128 * 64];
    __shared__ float red_s[WLN ? 4 : 1][WLN ? 32 : 1];
    __shared__ float red_q[WLN ? 4 : 1][WLN ? 32 : 1];
    int tid = threadIdx.x;
    int bm = blockIdx.x, bn = blockIdx.y;
    int lane = tid & 63, wid = tid >> 6;
    int lr = lane & 15, lg = lane >> 4;
    constexpr int MF = BM / 16;

    f32x4 acc[MF][2] = {};
    const __bf16* Asrc = A + (size_t)(bm * BM) * K;
    const __bf16* Bsrc = Wt + (size_t)(bn * 128) * K;

    for (int k0 = 0; k0 < K; k0 += 64) {
        if (GATE) {
            int row = tid >> 3, slot = tid & 7;
            int m = bm * BM + row;
            bf16x8 yv = *(const bf16x8*)(A + (size_t)m * K + k0 + slot * 8);
            bf16x8 gv = *(const bf16x8*)(G + (size_t)m * 256 + k0 + slot * 8);
            bf16x8 v;
#pragma unroll
            for (int j = 0; j < 8; ++j)
                v[j] = (__bf16)((float)yv[j] * (float)gv[j]);
            *(bf16x8*)(As + row * 64 + ((slot ^ (row & 7)) * 8)) = v;
        } else {
            stage_async<BM>(Asrc, As, k0, K, wid, lane);
        }
        stage_async<128>(Bsrc, Bs, k0, K, wid, lane);
        __syncthreads();
#pragma unroll
        for (int ks = 0; ks < 2; ++ks) {
            int slotbase = ks * 4 + lg;
            bf16x8 af[MF], bfr[2];
#pragma unroll
            for (int m = 0; m < MF; ++m) {
                int row = m * 16 + lr;
                af[m] = *(const bf16x8*)(As + row * 64 + ((slotbase ^ (row & 7)) * 8));
            }
#pragma unroll
            for (int n = 0; n < 2; ++n) {
                int rn = wid * 32 + n * 16 + lr;
                bfr[n] = *(const bf16x8*)(Bs + rn * 64 + ((slotbase ^ (rn & 7)) * 8));
            }
#pragma unroll
            for (int m = 0; m < MF; ++m)
#pragma unroll
                for (int n = 0; n < 2; ++n)
                    acc[m][n] = __builtin_amdgcn_mfma_f32_16x16x32_bf16(
                        af[m], bfr[n], acc[m][n], 0, 0, 0);
        }
        __syncthreads();
    }
    // ---- epilogue: frag layout D[row=(lane>>4)*4+reg][col=lane&15] ----
    if (MODE == 0) {
        // stage tile into LDS (reuse Bs), then coalesced bf16x8 stores
        __bf16* Es = Bs;
        bool toSg = (bn >= 2);
#pragma unroll
        for (int m = 0; m < MF; ++m)
#pragma unroll
            for (int n = 0; n < 2; ++n) {
                int lc = wid * 32 + n * 16 + lr;
#pragma unroll
                for (int rg = 0; rg < 4; ++rg) {
                    int rl = m * 16 + lg * 4 + rg;
                    float v = acc[m][n][rg];
                    Es[rl * 128 + lc] = (__bf16)(toSg ? siluf_(v) : v);
                }
            }
        __syncthreads();
        __bf16* dst = (toSg ? Zb : Cb) + (size_t)(bm * BM) * 256 + (bn & 1) * 128;
#pragma unroll
        for (int r = 0; r < (BM * 128) / (256 * 8); ++r) {
            int e = r * 256 + tid;
            int row = e >> 4, g8 = (e & 15) * 8;
            *(bf16x8*)(dst + (size_t)row * 256 + g8) = *(const bf16x8*)(Es + row * 128 + g8);
        }
    } else if (MODE == 1) {
        __bf16* Es = Bs;
#pragma unroll
        for (int m = 0; m < MF; ++m)
#pragma unroll
            for (int n = 0; n < 2; ++n) {
                int lc = wid * 32 + n * 16 + lr;
                if (lc < 64) {
#pragma unroll
                    for (int rg = 0; rg < 4; ++rg) {
                        int rl = m * 16 + lg * 4 + rg;
                        Es[rl * 64 + lc] = (__bf16)acc[m][n][rg];
                    }
                }
            }
        __syncthreads();
        __bf16* dst = Cb + (size_t)(bm * BM) * PSTR_;   // dense 64-col rows
#pragma unroll
        for (int r = 0; r < (BM * 64) / (256 * 8); ++r) {
            int e = r * 256 + tid;
            int row = e >> 3, g8 = (e & 7) * 8;
            *(bf16x8*)(dst + (size_t)row * PSTR_ + g8) = *(const bf16x8*)(Es + row * 64 + g8);
        }
    } else {
        float vv[MF][2][4];
#pragma unroll
        for (int m = 0; m < MF; ++m) {
#pragma unroll
            for (int n = 0; n < 2; ++n) {
                int col = bn * 128 + wid * 32 + n * 16 + lr;
                float bv = bias[col];
#pragma unroll
                for (int rg = 0; rg < 4; ++rg) {
                    int row = bm * BM + m * 16 + lg * 4 + rg;
                    float v = acc[m][n][rg];
                    float* cp = Cf + (size_t)row * N + col;
                    v += *cp + bv;
                    *cp = v;
                    vv[m][n][rg] = v;
                }
            }
        }
        if (WLN) {
            float ps[MF][4], pq[MF][4];
#pragma unroll
            for (int m = 0; m < MF; ++m)
#pragma unroll
                for (int rg = 0; rg < 4; ++rg) {
                    float a = vv[m][0][rg], bv2 = vv[m][1][rg];
                    ps[m][rg] = a + bv2;
                    pq[m][rg] = a * a + bv2 * bv2;
                }
#pragma unroll
            for (int off = 1; off < 16; off <<= 1) {
#pragma unroll
                for (int m = 0; m < MF; ++m)
#pragma unroll
                    for (int rg = 0; rg < 4; ++rg) {
                        ps[m][rg] += __shfl_xor(ps[m][rg], off);
                        pq[m][rg] += __shfl_xor(pq[m][rg], off);
                    }
            }
            if (lr == 0) {
#pragma unroll
                for (int m = 0; m < MF; ++m)
#pragma unroll
                    for (int rg = 0; rg < 4; ++rg) {
                        int rl = m * 16 + lg * 4 + rg;
                        red_s[wid][rl] = ps[m][rg];
                        red_q[wid][rl] = pq[m][rg];
                    }
            }
            __syncthreads();
#pragma unroll
            for (int m = 0; m < MF; ++m)
#pragma unroll
                for (int rg = 0; rg < 4; ++rg) {
                    int rl = m * 16 + lg * 4 + rg;
                    float s = red_s[0][rl] + red_s[1][rl] + red_s[2][rl] + red_s[3][rl];
                    float q = red_q[0][rl] + red_q[1][rl] + red_q[2][rl] + red_q[3][rl];
                    float mean = s * (1.0f / 128.0f);
                    float var = q * (1.0f / 128.0f) - mean * mean;
                    float rstd = rsqrtf(var + 1e-5f);
#pragma unroll
                    for (int n = 0; n < 2; ++n) {
                        int col = wid * 32 + n * 16 + lr;
                        float z = (vv[m][n][rg] - mean) * rstd * lnw[col] + lnb[col];
                        Zb[(size_t)(bm * BM + rl) * 128 + col] = (__bf16)z;
                    }
                }
        }
        if (POOL) {
#pragma unroll
            for (int n = 0; n < 2; ++n) {
                float s = 0.0f;
#pragma unroll
                for (int m = 0; m < MF; ++m)
#pragma unroll
                    for (int rg = 0; rg < 4; ++rg) s += vv[m][n][rg];
                s += __shfl_xor(s, 16);
                s += __shfl_xor(s, 32);      // summed over all 32 rows
                if (lg == 0)
                    Pool[(size_t)bm * 128 + wid * 32 + n * 16 + lr] = s;
            }
        }
    }
}

// ---------------- causal depthwise conv (width 4) + SiLU, vectorized -------------
__global__ __launch_bounds__(256) void k_conv(const __bf16* __restrict__ xinb,
        const float* __restrict__ cw, const float* __restrict__ cb,
        __bf16* __restrict__ xcb) {
    int t = blockIdx.x * 4 + (threadIdx.x >> 6);
    int d0 = (threadIdx.x & 63) * 4;
    int l = t & 1023;
    const __bf16* xp = xinb + (size_t)t * 256 + d0;
    float4 wv[4];
#pragma unroll
    for (int j = 0; j < 4; ++j) wv[j] = *(const float4*)(cw + (d0 + j) * 4);
    float acc[4] = {cb[d0], cb[d0 + 1], cb[d0 + 2], cb[d0 + 3]};
#pragma unroll
    for (int k = 0; k < 4; ++k) {
        int back = 3 - k;
        if (l >= back) {
            bf16x4 v = *(const bf16x4*)(xp - back * 256);
#pragma unroll
            for (int j = 0; j < 4; ++j)
                acc[j] = fmaf((float)v[j], ((const float*)&wv[j])[k], acc[j]);
        }
    }
    bf16x4 o;
#pragma unroll
    for (int j = 0; j < 4; ++j) o[j] = (__bf16)siluf_(acc[j]);
    *(bf16x4*)(xcb + (size_t)t * 256 + d0) = o;
}

// ---------------- chunk-parallel SSM scan: one thread per d ----------------------
// projall rows: [0..7]=dt, [8..23]=B, [24..39]=C (bf16, stride PSTR_=64).
// delta computed inline: softplus(dt . dtw[:,d] + dtb[d]).
template<bool FINAL>
__global__ __launch_bounds__(128) void k_scan_chunk(
        const __bf16* __restrict__ projall, const __bf16* __restrict__ xcb,
        const float* __restrict__ dtw, const float* __restrict__ dtb,
        const float* __restrict__ Alog, const float* __restrict__ Dp,
        float* __restrict__ P, float* __restrict__ S,
        __bf16* __restrict__ yb) {
    __shared__ __bf16 xcs[CHUNK_ * 128];        // 8 KB
    __shared__ float bc[CHUNK_ * 32];           // 4 KB
    __shared__ float dts[CHUNK_ * 8];           // 1 KB
    int b = blockIdx.z, c = blockIdx.y, dg = blockIdx.x;   // dg in {0,1}
    int tid = threadIdx.x;                      // 0..127
    int d = dg * 128 + tid;

    const __bf16* projC = projall + ((size_t)b * 1024 + c * CHUNK_) * PSTR_;
    const __bf16* xcC   = xcb + ((size_t)b * 1024 + c * CHUNK_) * 256 + dg * 128;

#pragma unroll
    for (int r = 0; r < (CHUNK_ * 16) / 128; ++r) {
        int item = r * 128 + tid;
        int t = item >> 4, o8 = (item & 15) * 8;
        *(bf16x8*)(xcs + t * 128 + o8) = *(const bf16x8*)(xcC + (size_t)t * 256 + o8);
    }
    {
        int t = tid >> 2, g8 = (tid & 3) * 8;
        bf16x8 v = *(const bf16x8*)(projC + (size_t)t * PSTR_ + 8 + g8);
        float4 f0 = {(float)v[0], (float)v[1], (float)v[2], (float)v[3]};
        float4 f1 = {(float)v[4], (float)v[5], (float)v[6], (float)v[7]};
        *(float4*)(bc + t * 32 + g8)     = f0;
        *(float4*)(bc + t * 32 + g8 + 4) = f1;
    }
    if (tid < CHUNK_) {
        bf16x8 v = *(const bf16x8*)(projC + (size_t)tid * PSTR_);
#pragma unroll
        for (int j = 0; j < 8; ++j) dts[tid * 8 + j] = (float)v[j];
    }

    float dtwc[8];
#pragma unroll
    for (int r = 0; r < 8; ++r) dtwc[r] = dtw[r * 256 + d];
    float dtbd = dtb[d];
    float aa[16], hs[16];
#pragma unroll
    for (int jj = 0; jj < 4; ++jj) {
        float4 av = *(const float4*)(Alog + (size_t)d * 16 + jj * 4);
        aa[jj * 4 + 0] = -__expf(av.x) * 1.44269504088896f;
        aa[jj * 4 + 1] = -__expf(av.y) * 1.44269504088896f;
        aa[jj * 4 + 2] = -__expf(av.z) * 1.44269504088896f;
        aa[jj * 4 + 3] = -__expf(av.w) * 1.44269504088896f;
    }
    float Dpd = Dp[d];
    size_t psIdx = ((size_t)(b * NCH_ + c)) * 4096 + (size_t)d * 16;
    if (FINAL) {
#pragma unroll
        for (int jj = 0; jj < 4; ++jj) {
            float4 h0 = *(const float4*)(P + psIdx + jj * 4);
            hs[jj * 4 + 0] = h0.x; hs[jj * 4 + 1] = h0.y;
            hs[jj * 4 + 2] = h0.z; hs[jj * 4 + 3] = h0.w;
        }
    } else {
#pragma unroll
        for (int j = 0; j < 16; ++j) hs[j] = 0.0f;
    }
    float cumd = 0.0f;
    __bf16* yC = yb + ((size_t)b * 1024 + c * CHUNK_) * 256 + dg * 128 + tid;

    __syncthreads();
#pragma unroll 2
    for (int tt = 0; tt < CHUNK_; ++tt) {
        const float* dtr = dts + tt * 8;
        float4 dt0 = *(const float4*)(dtr);
        float4 dt1 = *(const float4*)(dtr + 4);
        float dtv = dtbd;
        dtv = fmaf(dt0.x, dtwc[0], dtv); dtv = fmaf(dt0.y, dtwc[1], dtv);
        dtv = fmaf(dt0.z, dtwc[2], dtv); dtv = fmaf(dt0.w, dtwc[3], dtv);
        dtv = fmaf(dt1.x, dtwc[4], dtv); dtv = fmaf(dt1.y, dtwc[5], dtv);
        dtv = fmaf(dt1.z, dtwc[6], dtv); dtv = fmaf(dt1.w, dtwc[7], dtv);
        float delta_t = softplusf_(dtv);
        float u = (float)xcs[tt * 128 + tid];
        float du = delta_t * u;
        const float* bcr = bc + tt * 32;
        if (!FINAL) cumd += delta_t;
        float ys = 0.0f;
#pragma unroll
        for (int jj = 0; jj < 4; ++jj) {
            float4 Bv = *(const float4*)(bcr + jj * 4);
            float4 Cv;
            if (FINAL) Cv = *(const float4*)(bcr + 16 + jj * 4);
#pragma unroll
            for (int j = 0; j < 4; ++j) {
                int s = jj * 4 + j;
                float dA = fexp2_(delta_t * aa[s]);
                hs[s] = fmaf(dA, hs[s], du * ((const float*)&Bv)[j]);
                if (FINAL) ys = fmaf(hs[s], ((const float*)&Cv)[j], ys);
            }
        }
        if (FINAL) {
            float yv = fmaf(u, Dpd, ys);
            yv = fmaf(0.7f, yv, 0.3f * u);
            yC[(size_t)tt * 256] = (__bf16)yv;
        }
    }
    if (!FINAL) {
#pragma unroll
        for (int jj = 0; jj < 4; ++jj) {
            float4 pv, sv;
            pv.x = fexp2_(aa[jj * 4 + 0] * cumd);
            pv.y = fexp2_(aa[jj * 4 + 1] * cumd);
            pv.z = fexp2_(aa[jj * 4 + 2] * cumd);
            pv.w = fexp2_(aa[jj * 4 + 3] * cumd);
            sv.x = hs[jj * 4 + 0]; sv.y = hs[jj * 4 + 1];
            sv.z = hs[jj * 4 + 2]; sv.w = hs[jj * 4 + 3];
            *(float4*)(P + psIdx + jj * 4) = pv;
            *(float4*)(S + psIdx + jj * 4) = sv;
        }
    }
}

// ---------------- combine chunk aggregates: H_{c+1} = P_c*H_c + S_c --------------
__global__ __launch_bounds__(256) void k_scan_combine(float* __restrict__ P,
        const float* __restrict__ S) {
    int idx = blockIdx.x * 256 + threadIdx.x;
    int b = idx >> 12, rem = idx & 4095;
    float h = 0.0f;
#pragma unroll
    for (int c = 0; c < NCH_; ++c) {
        size_t base = ((size_t)(b * NCH_ + c)) * 4096 + rem;
        float p = P[base];
        float s = S[base];
        P[base] = h;
        h = fmaf(p, h, s);
    }
}

// ---------------- final LN + classifier (sums 32 gemm2-block partials) -----------
__global__ __launch_bounds__(128) void k_head(const float* __restrict__ pool2,
        const float* __restrict__ nw, const float* __restrict__ nb,
        const float* __restrict__ cw, const float* __restrict__ cb,
        float* __restrict__ out) {
    __shared__ float zs[128];
    __shared__ float red[128];
    int b = blockIdx.x, m = threadIdx.x;
    float v = 0.0f;
#pragma unroll 8
    for (int i = 0; i < 32; ++i) v += pool2[(size_t)(b * 32 + i) * 128 + m];
    v *= (1.0f / 1024.0f);
    red[m] = v;
    __syncthreads();
    for (int off = 64; off; off >>= 1) {
        if (m < off) red[m] += red[m + off];
        __syncthreads();
    }
    float mean = red[0] * (1.0f / 128.0f);
    __syncthreads();
    float dv = v - mean;
    red[m] = dv * dv;
    __syncthreads();
    for (int off = 64; off; off >>= 1) {
        if (m < off) red[m] += red[m + off];
        __syncthreads();
    }
    float rstd = rsqrtf(red[0] * (1.0f / 128.0f) + 1e-5f);
    zs[m] = dv * rstd * nw[m] + nb[m];
    __syncthreads();
    if (m < NC_) {
        float acc = cb[m];
#pragma unroll 8
        for (int k = 0; k < 128; ++k) acc = fmaf(zs[k], cw[k * 10 + m], acc);
        out[b * 10 + m] = acc;
    }
}

extern "C" void kernel_launch(void* const* d_in, const int* in_sizes, int n_in,
                              void* d_out, int out_size, void* d_ws, size_t ws_size,
                              hipStream_t stream) {
    const float* x    = (const float*)d_in[0];
    const float* Win  = (const float*)d_in[1];
    const float* bin  = (const float*)d_in[2];
    const float* lnw  = (const float*)d_in[3];
    const float* lnb  = (const float*)d_in[4];
    const float* ipw  = (const float*)d_in[5];
    const float* cw   = (const float*)d_in[6];
    const float* cb   = (const float*)d_in[7];
    const float* xpw  = (const float*)d_in[8];
    const float* dtw  = (const float*)d_in[9];
    const float* dtb  = (const float*)d_in[10];
    const float* Alog = (const float*)d_in[11];
    const float* Dp   = (const float*)d_in[12];
    const float* opw  = (const float*)d_in[13];
    const float* opb  = (const float*)d_in[14];
    const float* nw   = (const float*)d_in[15];
    const float* nb   = (const float*)d_in[16];
    const float* clw  = (const float*)d_in[17];
    const float* clb  = (const float*)d_in[18];

    // f32-slot offsets (all non-overlapping in time):
    //   h        [0,        4194304)
    //   P        [4194304,  8388608)   (zb bf16 aliases first half; zb consumed
    //                                   by gemm1 before scanA writes P)
    //   xinb bf16[8388608,  12582912)
    //   sgb  bf16[12582912, 16777216)
    //   xcb  bf16[16777216, 20971520)
    //   projall  [20971520, 22020096)  T*64 bf16
    //   yb bf16  [25690112, 29884416)
    //   wt1      [29917184, 30048256)
    //   wt2      [30048256, 30113792)
    //   wcat     [30113792, 30146560)
    //   Sb       [30310400, 34504704)
    //   pool2    [34504704, 34635776)  1024*128 f32
    float* ws = (float*)d_ws;
    float*  h       = ws;
    float*  P       = ws + 4194304;
    __bf16* zb      = (__bf16*)(ws + 4194304);
    __bf16* xinb    = (__bf16*)(ws + 8388608);
    __bf16* sgb     = (__bf16*)(ws + 12582912);
    __bf16* xcb     = (__bf16*)(ws + 16777216);
    __bf16* projall = (__bf16*)(ws + 20971520);
    __bf16* yb      = (__bf16*)(ws + 25690112);
    __bf16* wt1     = (__bf16*)(ws + 29917184);
    __bf16* wt2     = (__bf16*)(ws + 30048256);
    __bf16* wcat    = (__bf16*)(ws + 30113792);
    float*  Sb      = ws + 30310400;
    float*  pool2   = ws + 34504704;

    k_prep<<<1024, 256, 0, stream>>>(ipw, opw, xpw, wt1, wt2, wcat);
    k_embed_ln<<<T_ / 4, 256, 0, stream>>>(x, Win, bin, lnw, lnb, h, zb);
    for (int lay = 0; lay < 4; ++lay) {
        k_gemm_mfma<64, 128, 512, 0, false, false, false><<<dim3(T_ / 64, 4), 256, 0, stream>>>(
            zb, nullptr, wt1 + (size_t)lay * 65536, nullptr, nullptr, xinb,
            nullptr, nullptr, sgb, nullptr);
        k_conv<<<T_ / 4, 256, 0, stream>>>(xinb, cw + lay * 1024, cb + lay * 256, xcb);
        k_gemm_mfma<64, 256, 128, 1, false, false, false><<<dim3(T_ / 64, 1), 256, 0, stream>>>(
            xcb, nullptr, wcat + (size_t)lay * 16384, nullptr, nullptr, projall,
            nullptr, nullptr, nullptr, nullptr);
        k_scan_chunk<false><<<dim3(2, NCH_, B_), 128, 0, stream>>>(projall, xcb,
            dtw + lay * 2048, dtb + lay * 256, Alog + lay * 4096, Dp + lay * 256,
            P, Sb, yb);
        k_scan_combine<<<B_ * 4096 / 256, 256, 0, stream>>>(P, Sb);
        k_scan_chunk<true><<<dim3(2, NCH_, B_), 128, 0, stream>>>(projall, xcb,
            dtw + lay * 2048, dtb + lay * 256, Alog + lay * 4096, Dp + lay * 256,
            P, Sb, yb);
        if (lay < 3) {
            k_gemm_mfma<32, 256, 128, 2, true, true, false><<<dim3(T_ / 32, 1), 256, 0, stream>>>(
                yb, sgb, wt2 + (size_t)lay * 32768, opb + lay * 128, h, nullptr,
                lnw + (lay + 1) * 128, lnb + (lay + 1) * 128, zb, nullptr);
        } else {
            k_gemm_mfma<32, 256, 128, 2, true, false, true><<<dim3(T_ / 32, 1), 256, 0, stream>>>(
                yb, sgb, wt2 + (size_t)lay * 32768, opb + lay * 128, h, nullptr,
                nullptr, nullptr, nullptr, pool2);
        }
    }
    k_head<<<32, 128, 0, stream>>>(pool2, nw, nb, clw, clb, (float*)d_out);
}

// Round 19
// 525.328 us; speedup vs baseline: 1.4269x; 1.1234x over previous
//
#include <hip/hip_runtime.h>
#include <math.h>

// Problem constants
#define B_  32
#define L_  1024
#define T_  (B_ * L_)       // 32768 tokens
#define DM_ 128
#define DI_ 256
#define DS_ 16
#define DC_ 4
#define DR_ 8
#define NC_ 10
#define CHUNK_ 32
#define NCH_  (L_ / CHUNK_)   // 32 chunks
#define PSTR_ 64              // projall row stride (bf16): 8 dt | 16 B | 16 C | pad

typedef __bf16 bf16x8 __attribute__((ext_vector_type(8)));
typedef __bf16 bf16x4 __attribute__((ext_vector_type(4)));
typedef __bf16 bf16x2 __attribute__((ext_vector_type(2)));
typedef float f32x4 __attribute__((ext_vector_type(4)));

__device__ __forceinline__ float sigmoidf_(float x) { return 1.0f / (1.0f + __expf(-x)); }
__device__ __forceinline__ float siluf_(float x)    { return x * sigmoidf_(x); }
__device__ __forceinline__ float softplusf_(float x) {
    return (x > 15.0f) ? x : __logf(1.0f + __expf(x));
}
__device__ __forceinline__ float fexp2_(float x) { return __builtin_amdgcn_exp2f(x); }

// async 16B global->LDS (gfx950). dest = wave-uniform base + lane*16.
__device__ __forceinline__ void gload_lds16(const __bf16* g, __bf16* l) {
    __builtin_amdgcn_global_load_lds(
        (const __attribute__((address_space(1))) void*)g,
        (__attribute__((address_space(3))) void*)l, 16, 0, 0);
}

// Stage an R x 64 bf16 tile (row stride `stride`, col offset k0) into LDS with
// XOR-swizzle baked in: LDS (row, sw) holds source (row, sw ^ (row&7)).
template<int R>
__device__ __forceinline__ void stage_async(const __bf16* __restrict__ src,
        __bf16* lds, int k0, int stride, int wid, int lane) {
    constexpr int NI = R / 32;
#pragma unroll
    for (int j = 0; j < NI; ++j) {
        int s0 = (wid * NI + j) * 64;
        int s = s0 + lane;
        int row = s >> 3, sw = s & 7;
        int slot = sw ^ (row & 7);
        gload_lds16(src + (size_t)row * stride + k0 + slot * 8, lds + (size_t)s0 * 8);
    }
}

// ---------------- fused embed + layernorm (layer 0) -------------------------------
__global__ __launch_bounds__(256) void k_embed_ln(const float* __restrict__ x,
        const float* __restrict__ Win, const float* __restrict__ bin,
        const float* __restrict__ lnw, const float* __restrict__ lnb,
        float* __restrict__ h, __bf16* __restrict__ z) {
    int wid = threadIdx.x >> 6, lane = threadIdx.x & 63;
    int t = blockIdx.x * 4 + wid;
    int b = t >> 10, l = t & 1023;
    const float* xb = x + (size_t)b * 3 * 1024 + l;
    float x0 = xb[0], x1 = xb[1024], x2 = xb[2048];
    int m = lane * 2;
    float2 v;
    v.x = bin[m]     + x0 * Win[m]     + x1 * Win[128 + m]     + x2 * Win[256 + m];
    v.y = bin[m + 1] + x0 * Win[m + 1] + x1 * Win[128 + m + 1] + x2 * Win[256 + m + 1];
    *(float2*)(h + (size_t)t * 128 + m) = v;
    float s = v.x + v.y, sq = v.x * v.x + v.y * v.y;
#pragma unroll
    for (int off = 1; off < 64; off <<= 1) {
        s += __shfl_xor(s, off);
        sq += __shfl_xor(sq, off);
    }
    float mean = s * (1.0f / 128.0f);
    float var = sq * (1.0f / 128.0f) - mean * mean;
    float rstd = rsqrtf(var + 1e-5f);
    float2 wv = *(const float2*)(lnw + m);
    float2 bv = *(const float2*)(lnb + m);
    bf16x2 o;
    o.x = (__bf16)((v.x - mean) * rstd * wv.x + bv.x);
    o.y = (__bf16)((v.y - mean) * rstd * wv.y + bv.y);
    *(bf16x2*)(z + (size_t)t * 128 + m) = o;
}

// ---------------- merged weight prep ----------------------------------------------
// wt1[lay][n<512][k<128]; wt2[lay][n<128][k<256]; wcat[lay][n<64][k<256]
// (wcat n<40 = xpw col n transposed; else 0).
__global__ __launch_bounds__(256) void k_prep(const float* __restrict__ ipw,
        const float* __restrict__ opw, const float* __restrict__ xpw,
        __bf16* __restrict__ wt1, __bf16* __restrict__ wt2,
        __bf16* __restrict__ wcat) {
    int blk = blockIdx.x;              // 0..1023
    int tid = threadIdx.x;
    int i = blk * 256 + tid;
    {
        int lay = i >> 16, rem = i & 65535, n = rem >> 7, k = rem & 127;
        wt1[i] = (__bf16)ipw[lay * 65536 + k * 512 + n];
    }
    if (i < 131072) {
        int lay = i >> 15, rem = i & 32767, n = rem >> 8, k = rem & 255;
        wt2[i] = (__bf16)opw[lay * 32768 + k * 128 + n];
    }
    if (blk < 256) {
        int lay = blk >> 6, n = blk & 63;
        int k = tid;
        float v = (n < 40) ? xpw[lay * 10240 + k * 40 + n] : 0.0f;
        wcat[(size_t)blk * 256 + k] = (__bf16)v;
    }
}

// ---------------- bf16 MFMA GEMM, BM x 128 tile, BK=64 ---------------------------
// MODE 0 (gemm1, N=512): bn<2 -> Cb=xinb raw bf16; bn>=2 -> Zb=sgb silu(v).
//   Coalesced epilogue through LDS (reuses Bs).
// MODE 1 (xproj, N=128): cols<64 bf16 at stride PSTR_=64.
//   CONV: A-staging computes causal dwconv(4)+SiLU from xinb (cwf/cbf = conv
//   weights, staged to LDS transposed), writing both the LDS tile AND Zb=xcb.
//   Coalesced epilogue through LDS.
// MODE 2 (gemm2, N=128): Cf += acc + bias (f32); GATE A = y*sg (sg pre-silu'd).
//   WLN: fused LayerNorm -> next zb.   POOL: column-sums -> Pool[bm][128].
template<int BM, int K, int N, int MODE, bool GATE, bool WLN, bool POOL, bool CONV>
__global__ __launch_bounds__(256) void k_gemm_mfma(
        const __bf16* __restrict__ A, const __bf16* __restrict__ G,
        const __bf16* __restrict__ Wt, const float* __restrict__ bias,
        float* __restrict__ Cf, __bf16* __restrict__ Cb,
        const float* __restrict__ lnw, const float* __restrict__ lnb,
        __bf16* __restrict__ Zb, float* __restrict__ Pool) {
    static_assert(!GATE || BM == 32, "GATE staging assumes BM=32");
    static_assert(!WLN || (MODE == 2 && BM == 32 && N == 128), "WLN geometry");
    static_assert(!POOL || (MODE == 2 && BM == 32 && N == 128), "POOL geometry");
    static_assert(!CONV || (MODE == 1 && K == 256), "CONV geometry");
    __shared__ __bf16 As[BM * 64];
    __shared__ __bf16 Bs[128 * 64];
    __shared__ float red_s[WLN ? 4 : 1][WLN ? 32 : 1];
    __shared__ float red_q[WLN ? 4 : 1][WLN ? 32 : 1];
    __shared__ float cwl[CONV ? 1024 : 1];   // cwl[k*256+c] = cw[c*4+k]
    __shared__ float cbl[CONV ? 256 : 1];
    int tid = threadIdx.x;
    int bm = blockIdx.x, bn = blockIdx.y;
    int lane = tid & 63, wid = tid >> 6;
    int lr = lane & 15, lg = lane >> 4;
    constexpr int MF = BM / 16;

    f32x4 acc[MF][2] = {};
    const __bf16* Asrc = A + (size_t)(bm * BM) * K;
    const __bf16* Bsrc = Wt + (size_t)(bn * 128) * K;

    if (CONV) {
        float4 w4 = *(const float4*)(lnw + tid * 4);   // lnw carries conv weights
        cwl[0 * 256 + tid] = w4.x;
        cwl[1 * 256 + tid] = w4.y;
        cwl[2 * 256 + tid] = w4.z;
        cwl[3 * 256 + tid] = w4.w;
        cbl[tid] = lnb[tid];                           // lnb carries conv bias
        __syncthreads();
    }

    for (int k0 = 0; k0 < K; k0 += 64) {
        if (GATE) {
            int row = tid >> 3, slot = tid & 7;
            int m = bm * BM + row;
            bf16x8 yv = *(const bf16x8*)(A + (size_t)m * K + k0 + slot * 8);
            bf16x8 gv = *(const bf16x8*)(G + (size_t)m * 256 + k0 + slot * 8);
            bf16x8 v;
#pragma unroll
            for (int j = 0; j < 8; ++j)
                v[j] = (__bf16)((float)yv[j] * (float)gv[j]);
            *(bf16x8*)(As + row * 64 + ((slot ^ (row & 7)) * 8)) = v;
        } else if (CONV) {
            // conv+silu staging: rows = tokens, cols = channels k0+slot*8..+7
#pragma unroll
            for (int r = 0; r < (BM * 8) / 256; ++r) {
                int idx = tid + 256 * r;
                int row = idx >> 3, slot = idx & 7;
                int t = bm * BM + row;
                int l = t & 1023;
                int c = k0 + slot * 8;
                float accv[8];
#pragma unroll
                for (int j = 0; j < 8; ++j) accv[j] = cbl[c + j];
#pragma unroll
                for (int k = 0; k < 4; ++k) {        // tap k uses x[t-(3-k)]
                    int back = 3 - k;
                    if (l >= back) {
                        bf16x8 v = *(const bf16x8*)(A + (size_t)(t - back) * 256 + c);
#pragma unroll
                        for (int j = 0; j < 8; ++j)
                            accv[j] = fmaf((float)v[j], cwl[k * 256 + c + j], accv[j]);
                    }
                }
                bf16x8 o;
#pragma unroll
                for (int j = 0; j < 8; ++j) o[j] = (__bf16)siluf_(accv[j]);
                *(bf16x8*)(As + row * 64 + ((slot ^ (row & 7)) * 8)) = o;
                *(bf16x8*)(Zb + (size_t)t * 256 + c) = o;   // xcb out
            }
        } else {
            stage_async<BM>(Asrc, As, k0, K, wid, lane);
        }
        stage_async<128>(Bsrc, Bs, k0, K, wid, lane);
        __syncthreads();
#pragma unroll
        for (int ks = 0; ks < 2; ++ks) {
            int slotbase = ks * 4 + lg;
            bf16x8 af[MF], bfr[2];
#pragma unroll
            for (int m = 0; m < MF; ++m) {
                int row = m * 16 + lr;
                af[m] = *(const bf16x8*)(As + row * 64 + ((slotbase ^ (row & 7)) * 8));
            }
#pragma unroll
            for (int n = 0; n < 2; ++n) {
                int rn = wid * 32 + n * 16 + lr;
                bfr[n] = *(const bf16x8*)(Bs + rn * 64 + ((slotbase ^ (rn & 7)) * 8));
            }
#pragma unroll
            for (int m = 0; m < MF; ++m)
#pragma unroll
                for (int n = 0; n < 2; ++n)
                    acc[m][n] = __builtin_amdgcn_mfma_f32_16x16x32_bf16(
                        af[m], bfr[n], acc[m][n], 0, 0, 0);
        }
        __syncthreads();
    }
    // ---- epilogue: frag layout D[row=(lane>>4)*4+reg][col=lane&15] ----
    if (MODE == 0) {
        __bf16* Es = Bs;
        bool toSg = (bn >= 2);
#pragma unroll
        for (int m = 0; m < MF; ++m)
#pragma unroll
            for (int n = 0; n < 2; ++n) {
                int lc = wid * 32 + n * 16 + lr;
#pragma unroll
                for (int rg = 0; rg < 4; ++rg) {
                    int rl = m * 16 + lg * 4 + rg;
                    float v = acc[m][n][rg];
                    Es[rl * 128 + lc] = (__bf16)(toSg ? siluf_(v) : v);
                }
            }
        __syncthreads();
        __bf16* dst = (toSg ? Zb : Cb) + (size_t)(bm * BM) * 256 + (bn & 1) * 128;
#pragma unroll
        for (int r = 0; r < (BM * 128) / (256 * 8); ++r) {
            int e = r * 256 + tid;
            int row = e >> 4, g8 = (e & 15) * 8;
            *(bf16x8*)(dst + (size_t)row * 256 + g8) = *(const bf16x8*)(Es + row * 128 + g8);
        }
    } else if (MODE == 1) {
        __bf16* Es = Bs;
#pragma unroll
        for (int m = 0; m < MF; ++m)
#pragma unroll
            for (int n = 0; n < 2; ++n) {
                int lc = wid * 32 + n * 16 + lr;
                if (lc < 64) {
#pragma unroll
                    for (int rg = 0; rg < 4; ++rg) {
                        int rl = m * 16 + lg * 4 + rg;
                        Es[rl * 64 + lc] = (__bf16)acc[m][n][rg];
                    }
                }
            }
        __syncthreads();
        __bf16* dst = Cb + (size_t)(bm * BM) * PSTR_;   // dense 64-col rows
#pragma unroll
        for (int r = 0; r < (BM * 64) / (256 * 8); ++r) {
            int e = r * 256 + tid;
            int row = e >> 3, g8 = (e & 7) * 8;
            *(bf16x8*)(dst + (size_t)row * PSTR_ + g8) = *(const bf16x8*)(Es + row * 64 + g8);
        }
    } else {
        float vv[MF][2][4];
#pragma unroll
        for (int m = 0; m < MF; ++m) {
#pragma unroll
            for (int n = 0; n < 2; ++n) {
                int col = bn * 128 + wid * 32 + n * 16 + lr;
                float bv = bias[col];
#pragma unroll
                for (int rg = 0; rg < 4; ++rg) {
                    int row = bm * BM + m * 16 + lg * 4 + rg;
                    float v = acc[m][n][rg];
                    float* cp = Cf + (size_t)row * N + col;
                    v += *cp + bv;
                    *cp = v;
                    vv[m][n][rg] = v;
                }
            }
        }
        if (WLN) {
            float ps[MF][4], pq[MF][4];
#pragma unroll
            for (int m = 0; m < MF; ++m)
#pragma unroll
                for (int rg = 0; rg < 4; ++rg) {
                    float a = vv[m][0][rg], bv2 = vv[m][1][rg];
                    ps[m][rg] = a + bv2;
                    pq[m][rg] = a * a + bv2 * bv2;
                }
#pragma unroll
            for (int off = 1; off < 16; off <<= 1) {
#pragma unroll
                for (int m = 0; m < MF; ++m)
#pragma unroll
                    for (int rg = 0; rg < 4; ++rg) {
                        ps[m][rg] += __shfl_xor(ps[m][rg], off);
                        pq[m][rg] += __shfl_xor(pq[m][rg], off);
                    }
            }
            if (lr == 0) {
#pragma unroll
                for (int m = 0; m < MF; ++m)
#pragma unroll
                    for (int rg = 0; rg < 4; ++rg) {
                        int rl = m * 16 + lg * 4 + rg;
                        red_s[wid][rl] = ps[m][rg];
                        red_q[wid][rl] = pq[m][rg];
                    }
            }
            __syncthreads();
#pragma unroll
            for (int m = 0; m < MF; ++m)
#pragma unroll
                for (int rg = 0; rg < 4; ++rg) {
                    int rl = m * 16 + lg * 4 + rg;
                    float s = red_s[0][rl] + red_s[1][rl] + red_s[2][rl] + red_s[3][rl];
                    float q = red_q[0][rl] + red_q[1][rl] + red_q[2][rl] + red_q[3][rl];
                    float mean = s * (1.0f / 128.0f);
                    float var = q * (1.0f / 128.0f) - mean * mean;
                    float rstd = rsqrtf(var + 1e-5f);
#pragma unroll
                    for (int n = 0; n < 2; ++n) {
                        int col = wid * 32 + n * 16 + lr;
                        float z = (vv[m][n][rg] - mean) * rstd * lnw[col] + lnb[col];
                        Zb[(size_t)(bm * BM + rl) * 128 + col] = (__bf16)z;
                    }
                }
        }
        if (POOL) {
#pragma unroll
            for (int n = 0; n < 2; ++n) {
                float s = 0.0f;
#pragma unroll
                for (int m = 0; m < MF; ++m)
#pragma unroll
                    for (int rg = 0; rg < 4; ++rg) s += vv[m][n][rg];
                s += __shfl_xor(s, 16);
                s += __shfl_xor(s, 32);      // summed over all 32 rows
                if (lg == 0)
                    Pool[(size_t)bm * 128 + wid * 32 + n * 16 + lr] = s;
            }
        }
    }
}

// ---------------- chunk-parallel SSM scan: one thread per d ----------------------
// projall rows: [0..7]=dt, [8..23]=B, [24..39]=C (bf16, stride PSTR_=64).
// delta computed inline: softplus(dt . dtw[:,d] + dtb[d]).
template<bool FINAL>
__global__ __launch_bounds__(128) void k_scan_chunk(
        const __bf16* __restrict__ projall, const __bf16* __restrict__ xcb,
        const float* __restrict__ dtw, const float* __restrict__ dtb,
        const float* __restrict__ Alog, const float* __restrict__ Dp,
        float* __restrict__ P, float* __restrict__ S,
        __bf16* __restrict__ yb) {
    __shared__ __bf16 xcs[CHUNK_ * 128];        // 8 KB
    __shared__ float bc[CHUNK_ * 32];           // 4 KB
    __shared__ float dts[CHUNK_ * 8];           // 1 KB
    int b = blockIdx.z, c = blockIdx.y, dg = blockIdx.x;   // dg in {0,1}
    int tid = threadIdx.x;                      // 0..127
    int d = dg * 128 + tid;

    const __bf16* projC = projall + ((size_t)b * 1024 + c * CHUNK_) * PSTR_;
    const __bf16* xcC   = xcb + ((size_t)b * 1024 + c * CHUNK_) * 256 + dg * 128;

#pragma unroll
    for (int r = 0; r < (CHUNK_ * 16) / 128; ++r) {
        int item = r * 128 + tid;
        int t = item >> 4, o8 = (item & 15) * 8;
        *(bf16x8*)(xcs + t * 128 + o8) = *(const bf16x8*)(xcC + (size_t)t * 256 + o8);
    }
    {
        int t = tid >> 2, g8 = (tid & 3) * 8;
        bf16x8 v = *(const bf16x8*)(projC + (size_t)t * PSTR_ + 8 + g8);
        float4 f0 = {(float)v[0], (float)v[1], (float)v[2], (float)v[3]};
        float4 f1 = {(float)v[4], (float)v[5], (float)v[6], (float)v[7]};
        *(float4*)(bc + t * 32 + g8)     = f0;
        *(float4*)(bc + t * 32 + g8 + 4) = f1;
    }
    if (tid < CHUNK_) {
        bf16x8 v = *(const bf16x8*)(projC + (size_t)tid * PSTR_);
#pragma unroll
        for (int j = 0; j < 8; ++j) dts[tid * 8 + j] = (float)v[j];
    }

    float dtwc[8];
#pragma unroll
    for (int r = 0; r < 8; ++r) dtwc[r] = dtw[r * 256 + d];
    float dtbd = dtb[d];
    float aa[16], hs[16];
#pragma unroll
    for (int jj = 0; jj < 4; ++jj) {
        float4 av = *(const float4*)(Alog + (size_t)d * 16 + jj * 4);
        aa[jj * 4 + 0] = -__expf(av.x) * 1.44269504088896f;
        aa[jj * 4 + 1] = -__expf(av.y) * 1.44269504088896f;
        aa[jj * 4 + 2] = -__expf(av.z) * 1.44269504088896f;
        aa[jj * 4 + 3] = -__expf(av.w) * 1.44269504088896f;
    }
    float Dpd = Dp[d];
    size_t psIdx = ((size_t)(b * NCH_ + c)) * 4096 + (size_t)d * 16;
    if (FINAL) {
#pragma unroll
        for (int jj = 0; jj < 4; ++jj) {
            float4 h0 = *(const float4*)(P + psIdx + jj * 4);
            hs[jj * 4 + 0] = h0.x; hs[jj * 4 + 1] = h0.y;
            hs[jj * 4 + 2] = h0.z; hs[jj * 4 + 3] = h0.w;
        }
    } else {
#pragma unroll
        for (int j = 0; j < 16; ++j) hs[j] = 0.0f;
    }
    float cumd = 0.0f;
    __bf16* yC = yb + ((size_t)b * 1024 + c * CHUNK_) * 256 + dg * 128 + tid;

    __syncthreads();
#pragma unroll 2
    for (int tt = 0; tt < CHUNK_; ++tt) {
        const float* dtr = dts + tt * 8;
        float4 dt0 = *(const float4*)(dtr);
        float4 dt1 = *(const float4*)(dtr + 4);
        float dtv = dtbd;
        dtv = fmaf(dt0.x, dtwc[0], dtv); dtv = fmaf(dt0.y, dtwc[1], dtv);
        dtv = fmaf(dt0.z, dtwc[2], dtv); dtv = fmaf(dt0.w, dtwc[3], dtv);
        dtv = fmaf(dt1.x, dtwc[4], dtv); dtv = fmaf(dt1.y, dtwc[5], dtv);
        dtv = fmaf(dt1.z, dtwc[6], dtv); dtv = fmaf(dt1.w, dtwc[7], dtv);
        float delta_t = softplusf_(dtv);
        float u = (float)xcs[tt * 128 + tid];
        float du = delta_t * u;
        const float* bcr = bc + tt * 32;
        if (!FINAL) cumd += delta_t;
        float ys = 0.0f;
#pragma unroll
        for (int jj = 0; jj < 4; ++jj) {
            float4 Bv = *(const float4*)(bcr + jj * 4);
            float4 Cv;
            if (FINAL) Cv = *(const float4*)(bcr + 16 + jj * 4);
#pragma unroll
            for (int j = 0; j < 4; ++j) {
                int s = jj * 4 + j;
                float dA = fexp2_(delta_t * aa[s]);
                hs[s] = fmaf(dA, hs[s], du * ((const float*)&Bv)[j]);
                if (FINAL) ys = fmaf(hs[s], ((const float*)&Cv)[j], ys);
            }
        }
        if (FINAL) {
            float yv = fmaf(u, Dpd, ys);
            yv = fmaf(0.7f, yv, 0.3f * u);
            yC[(size_t)tt * 256] = (__bf16)yv;
        }
    }
    if (!FINAL) {
#pragma unroll
        for (int jj = 0; jj < 4; ++jj) {
            float4 pv, sv;
            pv.x = fexp2_(aa[jj * 4 + 0] * cumd);
            pv.y = fexp2_(aa[jj * 4 + 1] * cumd);
            pv.z = fexp2_(aa[jj * 4 + 2] * cumd);
            pv.w = fexp2_(aa[jj * 4 + 3] * cumd);
            sv.x = hs[jj * 4 + 0]; sv.y = hs[jj * 4 + 1];
            sv.z = hs[jj * 4 + 2]; sv.w = hs[jj * 4 + 3];
            *(float4*)(P + psIdx + jj * 4) = pv;
            *(float4*)(S + psIdx + jj * 4) = sv;
        }
    }
}

// ---------------- combine chunk aggregates: H_{c+1} = P_c*H_c + S_c --------------
__global__ __launch_bounds__(256) void k_scan_combine(float* __restrict__ P,
        const float* __restrict__ S) {
    int idx = blockIdx.x * 256 + threadIdx.x;
    int b = idx >> 12, rem = idx & 4095;
    float h = 0.0f;
#pragma unroll
    for (int c = 0; c < NCH_; ++c) {
        size_t base = ((size_t)(b * NCH_ + c)) * 4096 + rem;
        float p = P[base];
        float s = S[base];
        P[base] = h;
        h = fmaf(p, h, s);
    }
}

// ---------------- final LN + classifier (sums 32 gemm2-block partials) -----------
__global__ __launch_bounds__(128) void k_head(const float* __restrict__ pool2,
        const float* __restrict__ nw, const float* __restrict__ nb,
        const float* __restrict__ cw, const float* __restrict__ cb,
        float* __restrict__ out) {
    __shared__ float zs[128];
    __shared__ float red[128];
    int b = blockIdx.x, m = threadIdx.x;
    float v = 0.0f;
#pragma unroll 8
    for (int i = 0; i < 32; ++i) v += pool2[(size_t)(b * 32 + i) * 128 + m];
    v *= (1.0f / 1024.0f);
    red[m] = v;
    __syncthreads();
    for (int off = 64; off; off >>= 1) {
        if (m < off) red[m] += red[m + off];
        __syncthreads();
    }
    float mean = red[0] * (1.0f / 128.0f);
    __syncthreads();
    float dv = v - mean;
    red[m] = dv * dv;
    __syncthreads();
    for (int off = 64; off; off >>= 1) {
        if (m < off) red[m] += red[m + off];
        __syncthreads();
    }
    float rstd = rsqrtf(red[0] * (1.0f / 128.0f) + 1e-5f);
    zs[m] = dv * rstd * nw[m] + nb[m];
    __syncthreads();
    if (m < NC_) {
        float acc = cb[m];
#pragma unroll 8
        for (int k = 0; k < 128; ++k) acc = fmaf(zs[k], cw[k * 10 + m], acc);
        out[b * 10 + m] = acc;
    }
}

extern "C" void kernel_launch(void* const* d_in, const int* in_sizes, int n_in,
                              void* d_out, int out_size, void* d_ws, size_t ws_size,
                              hipStream_t stream) {
    const float* x    = (const float*)d_in[0];
    const float* Win  = (const float*)d_in[1];
    const float* bin  = (const float*)d_in[2];
    const float* lnw  = (const float*)d_in[3];
    const float* lnb  = (const float*)d_in[4];
    const float* ipw  = (const float*)d_in[5];
    const float* cw   = (const float*)d_in[6];
    const float* cb   = (const float*)d_in[7];
    const float* xpw  = (const float*)d_in[8];
    const float* dtw  = (const float*)d_in[9];
    const float* dtb  = (const float*)d_in[10];
    const float* Alog = (const float*)d_in[11];
    const float* Dp   = (const float*)d_in[12];
    const float* opw  = (const float*)d_in[13];
    const float* opb  = (const float*)d_in[14];
    const float* nw   = (const float*)d_in[15];
    const float* nb   = (const float*)d_in[16];
    const float* clw  = (const float*)d_in[17];
    const float* clb  = (const float*)d_in[18];

    // f32-slot offsets (all non-overlapping in time):
    //   h        [0,        4194304)
    //   P        [4194304,  8388608)   (zb bf16 aliases first half; zb consumed
    //                                   by gemm1 before scanA writes P)
    //   xinb bf16[8388608,  12582912)
    //   sgb  bf16[12582912, 16777216)
    //   xcb  bf16[16777216, 20971520)
    //   projall  [20971520, 22020096)  T*64 bf16
    //   yb bf16  [25690112, 29884416)
    //   wt1      [29917184, 30048256)
    //   wt2      [30048256, 30113792)
    //   wcat     [30113792, 30146560)
    //   Sb       [30310400, 34504704)
    //   pool2    [34504704, 34635776)  1024*128 f32
    float* ws = (float*)d_ws;
    float*  h       = ws;
    float*  P       = ws + 4194304;
    __bf16* zb      = (__bf16*)(ws + 4194304);
    __bf16* xinb    = (__bf16*)(ws + 8388608);
    __bf16* sgb     = (__bf16*)(ws + 12582912);
    __bf16* xcb     = (__bf16*)(ws + 16777216);
    __bf16* projall = (__bf16*)(ws + 20971520);
    __bf16* yb      = (__bf16*)(ws + 25690112);
    __bf16* wt1     = (__bf16*)(ws + 29917184);
    __bf16* wt2     = (__bf16*)(ws + 30048256);
    __bf16* wcat    = (__bf16*)(ws + 30113792);
    float*  Sb      = ws + 30310400;
    float*  pool2   = ws + 34504704;

    k_prep<<<1024, 256, 0, stream>>>(ipw, opw, xpw, wt1, wt2, wcat);
    k_embed_ln<<<T_ / 4, 256, 0, stream>>>(x, Win, bin, lnw, lnb, h, zb);
    for (int lay = 0; lay < 4; ++lay) {
        k_gemm_mfma<64, 128, 512, 0, false, false, false, false>
            <<<dim3(T_ / 64, 4), 256, 0, stream>>>(
            zb, nullptr, wt1 + (size_t)lay * 65536, nullptr, nullptr, xinb,
            nullptr, nullptr, sgb, nullptr);
        // fused conv+silu (A-staging) + x_proj MFMA; writes xcb and projall
        k_gemm_mfma<64, 256, 128, 1, false, false, false, true>
            <<<dim3(T_ / 64, 1), 256, 0, stream>>>(
            xinb, nullptr, wcat + (size_t)lay * 16384, nullptr, nullptr, projall,
            cw + lay * 1024, cb + lay * 256, xcb, nullptr);
        k_scan_chunk<false><<<dim3(2, NCH_, B_), 128, 0, stream>>>(projall, xcb,
            dtw + lay * 2048, dtb + lay * 256, Alog + lay * 4096, Dp + lay * 256,
            P, Sb, yb);
        k_scan_combine<<<B_ * 4096 / 256, 256, 0, stream>>>(P, Sb);
        k_scan_chunk<true><<<dim3(2, NCH_, B_), 128, 0, stream>>>(projall, xcb,
            dtw + lay * 2048, dtb + lay * 256, Alog + lay * 4096, Dp + lay * 256,
            P, Sb, yb);
        if (lay < 3) {
            k_gemm_mfma<32, 256, 128, 2, true, true, false, false>
                <<<dim3(T_ / 32, 1), 256, 0, stream>>>(
                yb, sgb, wt2 + (size_t)lay * 32768, opb + lay * 128, h, nullptr,
                lnw + (lay + 1) * 128, lnb + (lay + 1) * 128, zb, nullptr);
        } else {
            k_gemm_mfma<32, 256, 128, 2, true, false, true, false>
                <<<dim3(T_ / 32, 1), 256, 0, stream>>>(
                yb, sgb, wt2 + (size_t)lay * 32768, opb + lay * 128, h, nullptr,
                nullptr, nullptr, nullptr, pool2);
        }
    }
    k_head<<<32, 128, 0, stream>>>(pool2, nw, nb, clw, clb, (float*)d_out);
}